// Round 1
// baseline (300.903 us; speedup 1.0000x reference)
//
#include <hip/hip_runtime.h>

// SDFLoss: P=64 people, V=6890 verts, 32^3 SDF-band proxy grid, trilinear
// cross-sampling, scalar loss.
//
// Pipeline (all on `stream`, sequential deps):
//   k_bounds  : per-person bbox (min/max over V verts)
//   k_setup   : validity (bbox overlap w/ all), center, 1/scale, nv; zero acc
//   k_phi     : phi[p][z][y][x] = max(0.15 - dist_to_nearest_of_256_subverts, 0)
//   k_sample  : sum over valid pairs (i!=j) of trilinear(phi[i], verts[j]) -> atomicAdd
//   k_final   : out = acc / max(nv,1)^2

#define NP 64
#define NVERT 6890
#define GRD 32
#define G3 (GRD*GRD*GRD)
#define VSUB 256
#define VSTRIDE 26          // NVERT / VSUB
#define BAND 0.15f

__device__ __forceinline__ float wave_min(float v) {
  #pragma unroll
  for (int off = 32; off > 0; off >>= 1) v = fminf(v, __shfl_down(v, off));
  return v;
}
__device__ __forceinline__ float wave_max(float v) {
  #pragma unroll
  for (int off = 32; off > 0; off >>= 1) v = fmaxf(v, __shfl_down(v, off));
  return v;
}
__device__ __forceinline__ float wave_sum(float v) {
  #pragma unroll
  for (int off = 32; off > 0; off >>= 1) v += __shfl_down(v, off);
  return v;
}

// -------- kernel 1: per-person bbox --------
__global__ __launch_bounds__(256) void k_bounds(
    const float* __restrict__ verts, const float* __restrict__ trans,
    float* __restrict__ bmin, float* __restrict__ bmax) {
  int p = blockIdx.x;
  const float* vp = verts + (size_t)p * NVERT * 3;
  float tx = trans[p*3+0], ty = trans[p*3+1], tz = trans[p*3+2];
  float mnx=1e30f, mny=1e30f, mnz=1e30f, mxx=-1e30f, mxy=-1e30f, mxz=-1e30f;
  for (int v = threadIdx.x; v < NVERT; v += blockDim.x) {
    float x = vp[v*3+0]+tx, y = vp[v*3+1]+ty, z = vp[v*3+2]+tz;
    mnx=fminf(mnx,x); mny=fminf(mny,y); mnz=fminf(mnz,z);
    mxx=fmaxf(mxx,x); mxy=fmaxf(mxy,y); mxz=fmaxf(mxz,z);
  }
  mnx=wave_min(mnx); mny=wave_min(mny); mnz=wave_min(mnz);
  mxx=wave_max(mxx); mxy=wave_max(mxy); mxz=wave_max(mxz);
  __shared__ float s[4][6];
  int wave = threadIdx.x >> 6, lane = threadIdx.x & 63;
  if (lane == 0) {
    s[wave][0]=mnx; s[wave][1]=mny; s[wave][2]=mnz;
    s[wave][3]=mxx; s[wave][4]=mxy; s[wave][5]=mxz;
  }
  __syncthreads();
  if (threadIdx.x == 0) {
    float a0=s[0][0],a1=s[0][1],a2=s[0][2],b0=s[0][3],b1=s[0][4],b2=s[0][5];
    for (int w = 1; w < 4; ++w) {
      a0=fminf(a0,s[w][0]); a1=fminf(a1,s[w][1]); a2=fminf(a2,s[w][2]);
      b0=fmaxf(b0,s[w][3]); b1=fmaxf(b1,s[w][4]); b2=fmaxf(b2,s[w][5]);
    }
    bmin[p*3+0]=a0; bmin[p*3+1]=a1; bmin[p*3+2]=a2;
    bmax[p*3+0]=b0; bmax[p*3+1]=b1; bmax[p*3+2]=b2;
  }
}

// -------- kernel 2: validity, center, inv_scale, nv; zero acc --------
__global__ __launch_bounds__(64) void k_setup(
    const float* __restrict__ bmin, const float* __restrict__ bmax,
    float* __restrict__ center, float* __restrict__ inv_scale,
    float* __restrict__ validf, float* __restrict__ nv_acc) {
  __shared__ float smn[NP][3], smx[NP][3];
  int i = threadIdx.x;
  smn[i][0]=bmin[i*3+0]; smn[i][1]=bmin[i*3+1]; smn[i][2]=bmin[i*3+2];
  smx[i][0]=bmax[i*3+0]; smx[i][1]=bmax[i*3+1]; smx[i][2]=bmax[i*3+2];
  __syncthreads();
  bool valid = true;
  for (int j = 0; j < NP; ++j) {
    bool ov = true;
    #pragma unroll
    for (int c = 0; c < 3; ++c)
      ov = ov && (smn[i][c] <= smx[j][c]) && (smn[j][c] <= smx[i][c]);
    valid = valid && ov;
  }
  unsigned long long m = __ballot(valid);
  float nv = (float)__popcll(m);
  float ext = fmaxf(smx[i][0]-smn[i][0], fmaxf(smx[i][1]-smn[i][1], smx[i][2]-smn[i][2]));
  float scale = 0.6f * ext;   // (1+0.2)*0.5 * max extent
  center[i*3+0] = 0.5f*(smn[i][0]+smx[i][0]);
  center[i*3+1] = 0.5f*(smn[i][1]+smx[i][1]);
  center[i*3+2] = 0.5f*(smn[i][2]+smx[i][2]);
  inv_scale[i] = 1.0f / scale;
  validf[i] = valid ? 1.0f : 0.0f;
  if (i == 0) { nv_acc[0] = nv; nv_acc[1] = 0.0f; }
}

// -------- kernel 3: phi grid --------
// block = 256 threads; 16 blocks per person. thread t-in-person:
//   x = t&31, y=(t>>5)&31, zq=t>>10 (0..3), handles z = zq*8 .. zq*8+7
__global__ __launch_bounds__(256) void k_phi(
    const float* __restrict__ verts, const float* __restrict__ trans,
    const float* __restrict__ center, const float* __restrict__ inv_scale,
    float* __restrict__ phi) {
  int p = blockIdx.x >> 4;
  int t = ((blockIdx.x & 15) << 8) + threadIdx.x;
  int x = t & 31, y = (t >> 5) & 31, zq = t >> 10;

  __shared__ float sv[VSUB][3];
  {
    int k = threadIdx.x;  // 256 threads load 256 subsampled verts
    int v = k * VSTRIDE;
    float cx = center[p*3+0], cy = center[p*3+1], cz = center[p*3+2];
    float is = inv_scale[p];
    const float* vp = verts + (size_t)p * NVERT * 3 + (size_t)v * 3;
    sv[k][0] = (vp[0] + trans[p*3+0] - cx) * is;
    sv[k][1] = (vp[1] + trans[p*3+1] - cy) * is;
    sv[k][2] = (vp[2] + trans[p*3+2] - cz) * is;
  }
  __syncthreads();

  const float inv = 1.0f / (float)GRD;
  float gx = (2.0f*x + 1.0f) * inv - 1.0f;
  float gy = (2.0f*y + 1.0f) * inv - 1.0f;
  float gz[8];
  #pragma unroll
  for (int k = 0; k < 8; ++k) gz[k] = (2.0f*(zq*8+k) + 1.0f) * inv - 1.0f;

  float d2[8];
  #pragma unroll
  for (int k = 0; k < 8; ++k) d2[k] = 1e30f;

  for (int v = 0; v < VSUB; ++v) {
    float dx = gx - sv[v][0];
    float dy = gy - sv[v][1];
    float vz = sv[v][2];
    float r2 = fmaf(dy, dy, dx*dx);
    #pragma unroll
    for (int k = 0; k < 8; ++k) {
      float dz = gz[k] - vz;
      d2[k] = fminf(d2[k], fmaf(dz, dz, r2));
    }
  }
  float* pp = phi + (size_t)p * G3 + y*GRD + x;
  #pragma unroll
  for (int k = 0; k < 8; ++k)
    pp[(size_t)(zq*8+k) * (GRD*GRD)] = fmaxf(BAND - sqrtf(d2[k]), 0.0f);
}

// -------- kernel 4: trilinear sample + reduce --------
__device__ __forceinline__ float corner_v(const float* __restrict__ ph,
                                          int xi, int yi, int zi, float w) {
  if ((unsigned)xi < (unsigned)GRD && (unsigned)yi < (unsigned)GRD &&
      (unsigned)zi < (unsigned)GRD)
    return ph[zi*(GRD*GRD) + yi*GRD + xi] * w;
  return 0.0f;
}

__global__ __launch_bounds__(256) void k_sample(
    const float* __restrict__ verts, const float* __restrict__ trans,
    const float* __restrict__ center, const float* __restrict__ inv_scale,
    const float* __restrict__ validf, const float* __restrict__ phi,
    float* __restrict__ nv_acc) {
  int j = blockIdx.x, i = blockIdx.y;
  if (i == j) return;
  float w_pair = validf[i] * validf[j];
  if (w_pair == 0.0f) return;

  float cx = center[i*3+0], cy = center[i*3+1], cz = center[i*3+2];
  float is = inv_scale[i];
  float tx = trans[j*3+0], ty = trans[j*3+1], tz = trans[j*3+2];
  const float* vp = verts + (size_t)j * NVERT * 3;
  const float* ph = phi + (size_t)i * G3;

  float sum = 0.0f;
  for (int v = threadIdx.x; v < NVERT; v += blockDim.x) {
    float px = (vp[v*3+0] + tx - cx) * is;
    float py = (vp[v*3+1] + ty - cy) * is;
    float pz = (vp[v*3+2] + tz - cz) * is;
    // grid_sample align_corners=False: idx = ((p+1)*32 - 1)*0.5 = 16*p + 15.5
    float X = fmaf(px, 16.0f, 15.5f);
    float Y = fmaf(py, 16.0f, 15.5f);
    float Z = fmaf(pz, 16.0f, 15.5f);
    float x0f = floorf(X), y0f = floorf(Y), z0f = floorf(Z);
    int x0 = (int)x0f, y0 = (int)y0f, z0 = (int)z0f;
    float fx = X - x0f, fy = Y - y0f, fz = Z - z0f;
    float val = 0.0f;
    if (x0 >= 0 && x0 < GRD-1 && y0 >= 0 && y0 < GRD-1 && z0 >= 0 && z0 < GRD-1) {
      const float* b = ph + z0*(GRD*GRD) + y0*GRD + x0;
      float c000 = b[0],          c001 = b[1];
      float c010 = b[GRD],        c011 = b[GRD+1];
      float c100 = b[GRD*GRD],    c101 = b[GRD*GRD+1];
      float c110 = b[GRD*GRD+GRD],c111 = b[GRD*GRD+GRD+1];
      float wx0 = 1.0f-fx, wy0 = 1.0f-fy, wz0 = 1.0f-fz;
      val = wz0*(wy0*(wx0*c000 + fx*c001) + fy*(wx0*c010 + fx*c011))
          + fz *(wy0*(wx0*c100 + fx*c101) + fy*(wx0*c110 + fx*c111));
    } else if (x0 >= -1 && x0 <= GRD-1 && y0 >= -1 && y0 <= GRD-1 &&
               z0 >= -1 && z0 <= GRD-1) {
      float wx0 = 1.0f-fx, wy0 = 1.0f-fy, wz0 = 1.0f-fz;
      val = corner_v(ph, x0,   y0,   z0,   wx0*wy0*wz0)
          + corner_v(ph, x0+1, y0,   z0,   fx *wy0*wz0)
          + corner_v(ph, x0,   y0+1, z0,   wx0*fy *wz0)
          + corner_v(ph, x0+1, y0+1, z0,   fx *fy *wz0)
          + corner_v(ph, x0,   y0,   z0+1, wx0*wy0*fz )
          + corner_v(ph, x0+1, y0,   z0+1, fx *wy0*fz )
          + corner_v(ph, x0,   y0+1, z0+1, wx0*fy *fz )
          + corner_v(ph, x0+1, y0+1, z0+1, fx *fy *fz );
    }
    sum += val;
  }
  sum *= w_pair;
  sum = wave_sum(sum);
  __shared__ float s[4];
  int wave = threadIdx.x >> 6, lane = threadIdx.x & 63;
  if (lane == 0) s[wave] = sum;
  __syncthreads();
  if (threadIdx.x == 0) {
    float tot = s[0] + s[1] + s[2] + s[3];
    atomicAdd(&nv_acc[1], tot);
  }
}

// -------- kernel 5: finalize --------
__global__ void k_final(const float* __restrict__ nv_acc, float* __restrict__ out) {
  float nv = fmaxf(nv_acc[0], 1.0f);
  out[0] = nv_acc[1] / (nv * nv);
}

extern "C" void kernel_launch(void* const* d_in, const int* in_sizes, int n_in,
                              void* d_out, int out_size, void* d_ws, size_t ws_size,
                              hipStream_t stream) {
  const float* verts = (const float*)d_in[0];   // [64,6890,3]
  const float* trans = (const float*)d_in[1];   // [64,3]
  // d_in[2] = faces (unused by the reference computation)
  float* out = (float*)d_out;

  float* ws        = (float*)d_ws;
  float* phi       = ws;                         // 64*32768 = 2,097,152 floats (8 MB)
  float* bmin      = phi + (size_t)NP * G3;      // 192
  float* bmax      = bmin + NP*3;                // 192
  float* center    = bmax + NP*3;                // 192
  float* inv_scale = center + NP*3;              // 64
  float* validf    = inv_scale + NP;             // 64
  float* nv_acc    = validf + NP;                // [0]=nv, [1]=loss accumulator

  k_bounds<<<NP, 256, 0, stream>>>(verts, trans, bmin, bmax);
  k_setup<<<1, 64, 0, stream>>>(bmin, bmax, center, inv_scale, validf, nv_acc);
  k_phi<<<NP*16, 256, 0, stream>>>(verts, trans, center, inv_scale, phi);
  k_sample<<<dim3(NP, NP), 256, 0, stream>>>(verts, trans, center, inv_scale,
                                             validf, phi, nv_acc);
  k_final<<<1, 1, 0, stream>>>(nv_acc, out);
}

// Round 2
// 175.004 us; speedup vs baseline: 1.7194x; 1.7194x over previous
//
#include <hip/hip_runtime.h>
#include <hip/hip_fp16.h>

// SDFLoss: P=64 people, V=6890 verts, 32^3 SDF-band proxy grid, trilinear
// cross-sampling, scalar loss.
//
// Pipeline:
//   k_bounds  : per-person bbox
//   k_setup   : validity/center/inv_scale/nv; zero loss acc
//   k_phi     : phi grid, stored as half2 x-PAIRS: entry[z][y][x+1]=(phi[x],phi[x+1])
//               row stride 36 (bank spread), zero-padded x=-1/x=32 boundary entries
//   k_sample  : per (vertex-chunk, i) block: stage phi_i pairs in 147KB LDS,
//               loop j, 4 ds_read_b32 gathers per trilinear sample
//   k_final   : out = acc / max(nv,1)^2

#define NP 64
#define NVERT 6890
#define GRD 32
#define ROWS 36                 // padded half2-entries per (z,y) row
#define PVOL (GRD*GRD*ROWS)     // 36864 half2 entries per person (147456 B)
#define VSUB 256
#define VSTRIDE 26              // NVERT / VSUB
#define BAND 0.15f
#define LDS_BYTES (PVOL*4 + 64)

__device__ __forceinline__ float wave_min(float v) {
  #pragma unroll
  for (int off = 32; off > 0; off >>= 1) v = fminf(v, __shfl_down(v, off));
  return v;
}
__device__ __forceinline__ float wave_max(float v) {
  #pragma unroll
  for (int off = 32; off > 0; off >>= 1) v = fmaxf(v, __shfl_down(v, off));
  return v;
}
__device__ __forceinline__ float wave_sum(float v) {
  #pragma unroll
  for (int off = 32; off > 0; off >>= 1) v += __shfl_down(v, off);
  return v;
}

// -------- kernel 1: per-person bbox --------
__global__ __launch_bounds__(256) void k_bounds(
    const float* __restrict__ verts, const float* __restrict__ trans,
    float* __restrict__ bmin, float* __restrict__ bmax) {
  int p = blockIdx.x;
  const float* vp = verts + (size_t)p * NVERT * 3;
  float tx = trans[p*3+0], ty = trans[p*3+1], tz = trans[p*3+2];
  float mnx=1e30f, mny=1e30f, mnz=1e30f, mxx=-1e30f, mxy=-1e30f, mxz=-1e30f;
  for (int v = threadIdx.x; v < NVERT; v += blockDim.x) {
    float x = vp[v*3+0]+tx, y = vp[v*3+1]+ty, z = vp[v*3+2]+tz;
    mnx=fminf(mnx,x); mny=fminf(mny,y); mnz=fminf(mnz,z);
    mxx=fmaxf(mxx,x); mxy=fmaxf(mxy,y); mxz=fmaxf(mxz,z);
  }
  mnx=wave_min(mnx); mny=wave_min(mny); mnz=wave_min(mnz);
  mxx=wave_max(mxx); mxy=wave_max(mxy); mxz=wave_max(mxz);
  __shared__ float s[4][6];
  int wave = threadIdx.x >> 6, lane = threadIdx.x & 63;
  if (lane == 0) {
    s[wave][0]=mnx; s[wave][1]=mny; s[wave][2]=mnz;
    s[wave][3]=mxx; s[wave][4]=mxy; s[wave][5]=mxz;
  }
  __syncthreads();
  if (threadIdx.x == 0) {
    float a0=s[0][0],a1=s[0][1],a2=s[0][2],b0=s[0][3],b1=s[0][4],b2=s[0][5];
    for (int w = 1; w < 4; ++w) {
      a0=fminf(a0,s[w][0]); a1=fminf(a1,s[w][1]); a2=fminf(a2,s[w][2]);
      b0=fmaxf(b0,s[w][3]); b1=fmaxf(b1,s[w][4]); b2=fmaxf(b2,s[w][5]);
    }
    bmin[p*3+0]=a0; bmin[p*3+1]=a1; bmin[p*3+2]=a2;
    bmax[p*3+0]=b0; bmax[p*3+1]=b1; bmax[p*3+2]=b2;
  }
}

// -------- kernel 2: validity, center, inv_scale, nv; zero acc --------
__global__ __launch_bounds__(64) void k_setup(
    const float* __restrict__ bmin, const float* __restrict__ bmax,
    float* __restrict__ center, float* __restrict__ inv_scale,
    float* __restrict__ validf, float* __restrict__ nv_acc) {
  __shared__ float smn[NP][3], smx[NP][3];
  int i = threadIdx.x;
  smn[i][0]=bmin[i*3+0]; smn[i][1]=bmin[i*3+1]; smn[i][2]=bmin[i*3+2];
  smx[i][0]=bmax[i*3+0]; smx[i][1]=bmax[i*3+1]; smx[i][2]=bmax[i*3+2];
  __syncthreads();
  bool valid = true;
  for (int j = 0; j < NP; ++j) {
    bool ov = true;
    #pragma unroll
    for (int c = 0; c < 3; ++c)
      ov = ov && (smn[i][c] <= smx[j][c]) && (smn[j][c] <= smx[i][c]);
    valid = valid && ov;
  }
  unsigned long long m = __ballot(valid);
  float nv = (float)__popcll(m);
  float ext = fmaxf(smx[i][0]-smn[i][0], fmaxf(smx[i][1]-smn[i][1], smx[i][2]-smn[i][2]));
  float scale = 0.6f * ext;   // (1+0.2)*0.5 * max extent
  center[i*3+0] = 0.5f*(smn[i][0]+smx[i][0]);
  center[i*3+1] = 0.5f*(smn[i][1]+smx[i][1]);
  center[i*3+2] = 0.5f*(smn[i][2]+smx[i][2]);
  inv_scale[i] = 1.0f / scale;
  validf[i] = valid ? 1.0f : 0.0f;
  if (i == 0) { nv_acc[0] = nv; nv_acc[1] = 0.0f; }
}

// -------- kernel 3: phi grid (half2 x-pair layout) --------
// block = 256 threads; 16 blocks per person. thread t-in-person:
//   x = t&31, y=(t>>5)&31, zq=t>>10 (0..3), handles z = zq*8 .. zq*8+7
__global__ __launch_bounds__(256) void k_phi(
    const float* __restrict__ verts, const float* __restrict__ trans,
    const float* __restrict__ center, const float* __restrict__ inv_scale,
    __half2* __restrict__ phi) {
  int p = blockIdx.x >> 4;
  int t = ((blockIdx.x & 15) << 8) + threadIdx.x;
  int x = t & 31, y = (t >> 5) & 31, zq = t >> 10;
  int lane = threadIdx.x & 63;

  __shared__ float sv[VSUB][3];
  {
    int k = threadIdx.x;  // 256 threads load 256 subsampled verts
    int v = k * VSTRIDE;
    float cx = center[p*3+0], cy = center[p*3+1], cz = center[p*3+2];
    float is = inv_scale[p];
    const float* vp = verts + (size_t)p * NVERT * 3 + (size_t)v * 3;
    sv[k][0] = (vp[0] + trans[p*3+0] - cx) * is;
    sv[k][1] = (vp[1] + trans[p*3+1] - cy) * is;
    sv[k][2] = (vp[2] + trans[p*3+2] - cz) * is;
  }
  __syncthreads();

  const float inv = 1.0f / (float)GRD;
  float gx = (2.0f*x + 1.0f) * inv - 1.0f;
  float gy = (2.0f*y + 1.0f) * inv - 1.0f;
  float gz[8];
  #pragma unroll
  for (int k = 0; k < 8; ++k) gz[k] = (2.0f*(zq*8+k) + 1.0f) * inv - 1.0f;

  float d2[8];
  #pragma unroll
  for (int k = 0; k < 8; ++k) d2[k] = 1e30f;

  for (int v = 0; v < VSUB; ++v) {
    float dx = gx - sv[v][0];
    float dy = gy - sv[v][1];
    float vz = sv[v][2];
    float r2 = fmaf(dy, dy, dx*dx);
    #pragma unroll
    for (int k = 0; k < 8; ++k) {
      float dz = gz[k] - vz;
      d2[k] = fminf(d2[k], fmaf(dz, dz, r2));
    }
  }

  size_t base = (size_t)p * PVOL;
  #pragma unroll
  for (int k = 0; k < 8; ++k) {
    float val = fmaxf(BAND - sqrtf(d2[k]), 0.0f);
    float nb = __shfl(val, (lane + 1) & 63);   // neighbor x+1 (same y-row)
    if (x == 31) nb = 0.0f;
    int z = zq*8 + k;
    size_t row = base + ((size_t)z * GRD + y) * ROWS;
    phi[row + x + 1] = __floats2half2_rn(val, nb);          // cols 1..32
    if (x == 0) phi[row] = __floats2half2_rn(0.0f, val);    // col 0 (x=-1)
    if (x >= 1 && x <= 3)                                   // pad cols 33..35
      phi[row + 32 + x] = __floats2half2_rn(0.0f, 0.0f);
  }
}

// -------- kernel 4: trilinear sample from LDS + reduce --------
__global__ __launch_bounds__(1024) void k_sample(
    const float* __restrict__ verts, const float* __restrict__ trans,
    const float* __restrict__ center, const float* __restrict__ inv_scale,
    const float* __restrict__ validf, const __half2* __restrict__ phi,
    float* __restrict__ nv_acc) {
  extern __shared__ unsigned char smem[];
  __half2* sph = (__half2*)smem;
  float* red = (float*)(smem + (size_t)PVOL * 4);

  int i = blockIdx.y;
  if (validf[i] == 0.0f) return;

  // stage phi_i pair-volume into LDS (9216 uint4, 1024 threads x 9)
  {
    const uint4* src = (const uint4*)(phi + (size_t)i * PVOL);
    uint4* dst = (uint4*)smem;
    #pragma unroll
    for (int t = threadIdx.x; t < PVOL/4; t += 1024) dst[t] = src[t];
  }
  __syncthreads();

  int v = blockIdx.x * 1024 + threadIdx.x;
  float cx = center[i*3+0], cy = center[i*3+1], cz = center[i*3+2];
  float s16 = inv_scale[i] * 16.0f;

  float acc = 0.0f;
  if (v < NVERT) {
    for (int j = 0; j < NP; ++j) {
      if (j == i || validf[j] == 0.0f) continue;
      float ox = fmaf(trans[j*3+0] - cx, s16, 15.5f);
      float oy = fmaf(trans[j*3+1] - cy, s16, 15.5f);
      float oz = fmaf(trans[j*3+2] - cz, s16, 15.5f);
      const float* vp = verts + ((size_t)j * NVERT + v) * 3;
      float X = fmaf(vp[0], s16, ox);
      float Y = fmaf(vp[1], s16, oy);
      float Z = fmaf(vp[2], s16, oz);
      float xf = floorf(X), yf = floorf(Y), zf = floorf(Z);
      int x0 = (int)xf, y0 = (int)yf, z0 = (int)zf;
      if ((unsigned)(x0+1) > 32u || (unsigned)(y0+1) > 32u ||
          (unsigned)(z0+1) > 32u) continue;
      float fx = X - xf, fy = Y - yf, fz = Z - zf;
      int col = x0 + 1;
      bool y0i = (unsigned)y0 < 32u, y1i = (unsigned)(y0+1) < 32u;
      bool z0i = (unsigned)z0 < 32u, z1i = (unsigned)(z0+1) < 32u;
      float2 zero2 = make_float2(0.0f, 0.0f);
      float2 c00 = (y0i && z0i) ? __half22float2(sph[(z0*GRD + y0)*ROWS + col]) : zero2;
      float2 c10 = (y1i && z0i) ? __half22float2(sph[(z0*GRD + y0 + 1)*ROWS + col]) : zero2;
      float2 c01 = (y0i && z1i) ? __half22float2(sph[((z0+1)*GRD + y0)*ROWS + col]) : zero2;
      float2 c11 = (y1i && z1i) ? __half22float2(sph[((z0+1)*GRD + y0 + 1)*ROWS + col]) : zero2;
      // interp x within each pair, then y, then z
      float a00 = fmaf(fx, c00.y - c00.x, c00.x);
      float a10 = fmaf(fx, c10.y - c10.x, c10.x);
      float a01 = fmaf(fx, c01.y - c01.x, c01.x);
      float a11 = fmaf(fx, c11.y - c11.x, c11.x);
      float b0 = fmaf(fy, a10 - a00, a00);
      float b1 = fmaf(fy, a11 - a01, a01);
      acc += fmaf(fz, b1 - b0, b0);
    }
  }

  acc = wave_sum(acc);
  int wave = threadIdx.x >> 6, lane = threadIdx.x & 63;
  if (lane == 0) red[wave] = acc;
  __syncthreads();
  if (threadIdx.x == 0) {
    float tot = 0.0f;
    #pragma unroll
    for (int w = 0; w < 16; ++w) tot += red[w];
    atomicAdd(&nv_acc[1], tot);
  }
}

// -------- kernel 5: finalize --------
__global__ void k_final(const float* __restrict__ nv_acc, float* __restrict__ out) {
  float nv = fmaxf(nv_acc[0], 1.0f);
  out[0] = nv_acc[1] / (nv * nv);
}

extern "C" void kernel_launch(void* const* d_in, const int* in_sizes, int n_in,
                              void* d_out, int out_size, void* d_ws, size_t ws_size,
                              hipStream_t stream) {
  const float* verts = (const float*)d_in[0];   // [64,6890,3]
  const float* trans = (const float*)d_in[1];   // [64,3]
  float* out = (float*)d_out;

  __half2* phi     = (__half2*)d_ws;                 // 64 * 36864 half2 = 9.44 MB
  float* fb        = (float*)d_ws + (size_t)NP * PVOL;
  float* bmin      = fb;                             // 192
  float* bmax      = bmin + NP*3;
  float* center    = bmax + NP*3;
  float* inv_scale = center + NP*3;
  float* validf    = inv_scale + NP;
  float* nv_acc    = validf + NP;                    // [0]=nv, [1]=loss acc

  hipFuncSetAttribute((const void*)k_sample,
                      hipFuncAttributeMaxDynamicSharedMemorySize, LDS_BYTES);

  k_bounds<<<NP, 256, 0, stream>>>(verts, trans, bmin, bmax);
  k_setup<<<1, 64, 0, stream>>>(bmin, bmax, center, inv_scale, validf, nv_acc);
  k_phi<<<NP*16, 256, 0, stream>>>(verts, trans, center, inv_scale, phi);
  k_sample<<<dim3(7, NP), 1024, LDS_BYTES, stream>>>(verts, trans, center,
                                                     inv_scale, validf, phi, nv_acc);
  k_final<<<1, 1, 0, stream>>>(nv_acc, out);
}

// Round 5
// 138.785 us; speedup vs baseline: 2.1681x; 1.2610x over previous
//
#include <hip/hip_runtime.h>

// SDFLoss: P=64 people, V=6890 verts, 32^3 SDF-band proxy grid, trilinear
// cross-sampling, scalar loss.
//
// phi stored as fp8(e4m3) x-PAIRS scaled by 64: entry[z][y][col] =
// (phi[x]*64, phi[x+1]*64) packed in 2 bytes, col = x+1 (col 0 = x=-1 pad).
// Row stride 36 entries, plane stride 32*36+2 = 1154 (bank shift 1 per z).
// k_sample stages one person's 73.9 KB pair-volume in LDS -> 2 blocks/CU.

#define NP 64
#define NVERT 6890
#define GRD 32
#define ROWS 36                   // entries per (z,y) row
#define PLANE (GRD*ROWS + 2)      // 1154 entries per z-plane (pad 2: bank spread)
#define PVOL (GRD*PLANE)          // 36928 entries per person (73856 B)
#define VSUB 256
#define VSTRIDE 26                // NVERT / VSUB
#define BAND 0.15f
#define PHI_SCALE 64.0f
#define INV_PHI_SCALE 0.015625f
#define LDS_BYTES (PVOL*2 + 64)

typedef float floatx2 __attribute__((ext_vector_type(2)));

__device__ __forceinline__ float wave_min(float v) {
  #pragma unroll
  for (int off = 32; off > 0; off >>= 1) v = fminf(v, __shfl_down(v, off));
  return v;
}
__device__ __forceinline__ float wave_max(float v) {
  #pragma unroll
  for (int off = 32; off > 0; off >>= 1) v = fmaxf(v, __shfl_down(v, off));
  return v;
}
__device__ __forceinline__ float wave_sum(float v) {
  #pragma unroll
  for (int off = 32; off > 0; off >>= 1) v += __shfl_down(v, off);
  return v;
}

// -------- kernel 1: per-person bbox --------
__global__ __launch_bounds__(256) void k_bounds(
    const float* __restrict__ verts, const float* __restrict__ trans,
    float* __restrict__ bmin, float* __restrict__ bmax) {
  int p = blockIdx.x;
  const float* vp = verts + (size_t)p * NVERT * 3;
  float tx = trans[p*3+0], ty = trans[p*3+1], tz = trans[p*3+2];
  float mnx=1e30f, mny=1e30f, mnz=1e30f, mxx=-1e30f, mxy=-1e30f, mxz=-1e30f;
  for (int v = threadIdx.x; v < NVERT; v += blockDim.x) {
    float x = vp[v*3+0]+tx, y = vp[v*3+1]+ty, z = vp[v*3+2]+tz;
    mnx=fminf(mnx,x); mny=fminf(mny,y); mnz=fminf(mnz,z);
    mxx=fmaxf(mxx,x); mxy=fmaxf(mxy,y); mxz=fmaxf(mxz,z);
  }
  mnx=wave_min(mnx); mny=wave_min(mny); mnz=wave_min(mnz);
  mxx=wave_max(mxx); mxy=wave_max(mxy); mxz=wave_max(mxz);
  __shared__ float s[4][6];
  int wave = threadIdx.x >> 6, lane = threadIdx.x & 63;
  if (lane == 0) {
    s[wave][0]=mnx; s[wave][1]=mny; s[wave][2]=mnz;
    s[wave][3]=mxx; s[wave][4]=mxy; s[wave][5]=mxz;
  }
  __syncthreads();
  if (threadIdx.x == 0) {
    float a0=s[0][0],a1=s[0][1],a2=s[0][2],b0=s[0][3],b1=s[0][4],b2=s[0][5];
    for (int w = 1; w < 4; ++w) {
      a0=fminf(a0,s[w][0]); a1=fminf(a1,s[w][1]); a2=fminf(a2,s[w][2]);
      b0=fmaxf(b0,s[w][3]); b1=fmaxf(b1,s[w][4]); b2=fmaxf(b2,s[w][5]);
    }
    bmin[p*3+0]=a0; bmin[p*3+1]=a1; bmin[p*3+2]=a2;
    bmax[p*3+0]=b0; bmax[p*3+1]=b1; bmax[p*3+2]=b2;
  }
}

// -------- kernel 2: validity, center, inv_scale, nv, valid-j list --------
__global__ __launch_bounds__(64) void k_setup(
    const float* __restrict__ bmin, const float* __restrict__ bmax,
    float* __restrict__ center, float* __restrict__ inv_scale,
    float* __restrict__ validf, float* __restrict__ nv_acc,
    int* __restrict__ jlist, int* __restrict__ jcount) {
  __shared__ float smn[NP][3], smx[NP][3];
  int i = threadIdx.x;
  smn[i][0]=bmin[i*3+0]; smn[i][1]=bmin[i*3+1]; smn[i][2]=bmin[i*3+2];
  smx[i][0]=bmax[i*3+0]; smx[i][1]=bmax[i*3+1]; smx[i][2]=bmax[i*3+2];
  __syncthreads();
  bool valid = true;
  for (int j = 0; j < NP; ++j) {
    bool ov = true;
    #pragma unroll
    for (int c = 0; c < 3; ++c)
      ov = ov && (smn[i][c] <= smx[j][c]) && (smn[j][c] <= smx[i][c]);
    valid = valid && ov;
  }
  unsigned long long m = __ballot(valid);
  float nv = (float)__popcll(m);
  if (valid) {
    int pos = (int)__popcll(m & ((1ull << i) - 1ull));
    jlist[pos] = i;
  }
  float ext = fmaxf(smx[i][0]-smn[i][0], fmaxf(smx[i][1]-smn[i][1], smx[i][2]-smn[i][2]));
  float scale = 0.6f * ext;   // (1+0.2)*0.5 * max extent
  center[i*3+0] = 0.5f*(smn[i][0]+smx[i][0]);
  center[i*3+1] = 0.5f*(smn[i][1]+smx[i][1]);
  center[i*3+2] = 0.5f*(smn[i][2]+smx[i][2]);
  inv_scale[i] = 1.0f / scale;
  validf[i] = valid ? 1.0f : 0.0f;
  if (i == 0) {
    nv_acc[0] = nv; nv_acc[1] = 0.0f;
    jcount[0] = (int)__popcll(m);
  }
}

// -------- kernel 3: phi grid (fp8 x-pair layout, scaled x64) --------
__global__ __launch_bounds__(256) void k_phi(
    const float* __restrict__ verts, const float* __restrict__ trans,
    const float* __restrict__ center, const float* __restrict__ inv_scale,
    unsigned short* __restrict__ phi) {
  int p = blockIdx.x >> 4;
  int t = ((blockIdx.x & 15) << 8) + threadIdx.x;
  int x = t & 31, y = (t >> 5) & 31, zq = t >> 10;
  int lane = threadIdx.x & 63;

  __shared__ float sv[VSUB][3];
  {
    int k = threadIdx.x;
    int v = k * VSTRIDE;
    float cx = center[p*3+0], cy = center[p*3+1], cz = center[p*3+2];
    float is = inv_scale[p];
    const float* vp = verts + (size_t)p * NVERT * 3 + (size_t)v * 3;
    sv[k][0] = (vp[0] + trans[p*3+0] - cx) * is;
    sv[k][1] = (vp[1] + trans[p*3+1] - cy) * is;
    sv[k][2] = (vp[2] + trans[p*3+2] - cz) * is;
  }
  __syncthreads();

  const float inv = 1.0f / (float)GRD;
  float gx = (2.0f*x + 1.0f) * inv - 1.0f;
  float gy = (2.0f*y + 1.0f) * inv - 1.0f;
  float gz[8];
  #pragma unroll
  for (int k = 0; k < 8; ++k) gz[k] = (2.0f*(zq*8+k) + 1.0f) * inv - 1.0f;

  float d2[8];
  #pragma unroll
  for (int k = 0; k < 8; ++k) d2[k] = 1e30f;

  for (int v = 0; v < VSUB; ++v) {
    float dx = gx - sv[v][0];
    float dy = gy - sv[v][1];
    float vz = sv[v][2];
    float r2 = fmaf(dy, dy, dx*dx);
    #pragma unroll
    for (int k = 0; k < 8; ++k) {
      float dz = gz[k] - vz;
      d2[k] = fminf(d2[k], fmaf(dz, dz, r2));
    }
  }

  unsigned short* pp = phi + (size_t)p * PVOL;
  #pragma unroll
  for (int k = 0; k < 8; ++k) {
    float val = fmaxf(BAND - sqrtf(d2[k]), 0.0f) * PHI_SCALE;
    float nb = __shfl(val, (lane + 1) & 63);       // x+1 neighbor (same y-row)
    if (x == 31) nb = 0.0f;
    int z = zq*8 + k;
    int row = z*PLANE + y*ROWS;
    int pk = __builtin_amdgcn_cvt_pk_fp8_f32(val, nb, 0, false);
    pp[row + x + 1] = (unsigned short)(pk & 0xffff);
    if (x == 0) {
      int pk0 = __builtin_amdgcn_cvt_pk_fp8_f32(0.0f, val, 0, false);
      pp[row] = (unsigned short)(pk0 & 0xffff);
    }
  }
}

// -------- kernel 4: trilinear sample from LDS + reduce --------
__global__ __launch_bounds__(1024, 8) void k_sample(
    const float* __restrict__ verts, const float* __restrict__ trans,
    const float* __restrict__ center, const float* __restrict__ inv_scale,
    const float* __restrict__ validf, const unsigned short* __restrict__ phi,
    const int* __restrict__ jlist, const int* __restrict__ jcount,
    float* __restrict__ nv_acc) {
  extern __shared__ unsigned char smem[];
  unsigned short* sph = (unsigned short*)smem;
  float* red = (float*)(smem + (size_t)PVOL * 2);

  int i = blockIdx.y;
  if (validf[i] == 0.0f) return;
  int njl = jcount[0];

  // stage phi_i pair-volume into LDS (4616 uint4)
  {
    const uint4* src = (const uint4*)(phi + (size_t)i * PVOL);
    uint4* dst = (uint4*)smem;
    for (int t = threadIdx.x; t < PVOL/8; t += 1024) dst[t] = src[t];
  }
  __syncthreads();

  int v = blockIdx.x * 1024 + threadIdx.x;
  float cx = center[i*3+0], cy = center[i*3+1], cz = center[i*3+2];
  float s16 = inv_scale[i] * 16.0f;

  float acc = 0.0f;
  if (v < NVERT) {
    int jj = jlist[0];
    const float* vp0 = verts + ((size_t)jj * NVERT + v) * 3;
    float vx = vp0[0], vy = vp0[1], vz = vp0[2];
    for (int t = 0; t < njl; ++t) {
      float wj = (jj == i) ? 0.0f : 1.0f;
      float ox = fmaf(trans[jj*3+0] - cx, s16, 15.5f);
      float oy = fmaf(trans[jj*3+1] - cy, s16, 15.5f);
      float oz = fmaf(trans[jj*3+2] - cz, s16, 15.5f);
      float X = fmaf(vx, s16, ox);
      float Y = fmaf(vy, s16, oy);
      float Z = fmaf(vz, s16, oz);
      // prefetch next j's vertex while we interpolate this one
      int tn = (t + 1 < njl) ? (t + 1) : t;
      int jn = jlist[tn];
      const float* vpn = verts + ((size_t)jn * NVERT + v) * 3;
      float nx = vpn[0], ny = vpn[1], nz = vpn[2];

      float xf = floorf(X), yf = floorf(Y), zf = floorf(Z);
      int x0 = (int)xf, y0 = (int)yf, z0 = (int)zf;
      if ((unsigned)(x0+1) <= 32u && (unsigned)(y0+1) <= 32u &&
          (unsigned)(z0+1) <= 32u) {
        float fx = X - xf, fy = Y - yf, fz = Z - zf;
        int col = x0 + 1;
        bool y0i = y0 >= 0,  y1i = y0 < 31;
        bool z0i = z0 >= 0,  z1i = z0 < 31;
        int yc0 = y0i ? y0 : 0,      yc1 = y1i ? y0 + 1 : 31;
        int zc0 = z0i ? z0 : 0,      zc1 = z1i ? z0 + 1 : 31;
        int r0 = yc0*ROWS + col, r1 = yc1*ROWS + col;
        int p0 = zc0*PLANE,      p1 = zc1*PLANE;
        floatx2 c00 = __builtin_amdgcn_cvt_pk_f32_fp8((int)sph[p0 + r0], false);
        floatx2 c10 = __builtin_amdgcn_cvt_pk_f32_fp8((int)sph[p0 + r1], false);
        floatx2 c01 = __builtin_amdgcn_cvt_pk_f32_fp8((int)sph[p1 + r0], false);
        floatx2 c11 = __builtin_amdgcn_cvt_pk_f32_fp8((int)sph[p1 + r1], false);
        float a00 = fmaf(fx, c00.y - c00.x, c00.x);
        float a10 = fmaf(fx, c10.y - c10.x, c10.x);
        float a01 = fmaf(fx, c01.y - c01.x, c01.x);
        float a11 = fmaf(fx, c11.y - c11.x, c11.x);
        a00 = (y0i && z0i) ? a00 : 0.0f;
        a10 = (y1i && z0i) ? a10 : 0.0f;
        a01 = (y0i && z1i) ? a01 : 0.0f;
        a11 = (y1i && z1i) ? a11 : 0.0f;
        float b0 = fmaf(fy, a10 - a00, a00);
        float b1 = fmaf(fy, a11 - a01, a01);
        acc = fmaf(wj, fmaf(fz, b1 - b0, b0), acc);
      }
      jj = jn; vx = nx; vy = ny; vz = nz;
    }
  }

  acc = wave_sum(acc);
  int wave = threadIdx.x >> 6, lane = threadIdx.x & 63;
  if (lane == 0) red[wave] = acc;
  __syncthreads();
  if (threadIdx.x == 0) {
    float tot = 0.0f;
    #pragma unroll
    for (int w = 0; w < 16; ++w) tot += red[w];
    atomicAdd(&nv_acc[1], tot * INV_PHI_SCALE);
  }
}

// -------- kernel 5: finalize --------
__global__ void k_final(const float* __restrict__ nv_acc, float* __restrict__ out) {
  float nv = fmaxf(nv_acc[0], 1.0f);
  out[0] = nv_acc[1] / (nv * nv);
}

extern "C" void kernel_launch(void* const* d_in, const int* in_sizes, int n_in,
                              void* d_out, int out_size, void* d_ws, size_t ws_size,
                              hipStream_t stream) {
  const float* verts = (const float*)d_in[0];   // [64,6890,3]
  const float* trans = (const float*)d_in[1];   // [64,3]
  float* out = (float*)d_out;

  unsigned short* phi = (unsigned short*)d_ws;        // 64*36928*2 B = 4.73 MB
  float* fb        = (float*)((unsigned char*)d_ws + (size_t)NP * PVOL * 2);
  float* bmin      = fb;
  float* bmax      = bmin + NP*3;
  float* center    = bmax + NP*3;
  float* inv_scale = center + NP*3;
  float* validf    = inv_scale + NP;
  float* nv_acc    = validf + NP;                     // [0]=nv, [1]=loss acc
  int*   jlist     = (int*)(nv_acc + 2);
  int*   jcount    = jlist + NP;

  hipFuncSetAttribute((const void*)k_sample,
                      hipFuncAttributeMaxDynamicSharedMemorySize, LDS_BYTES);

  k_bounds<<<NP, 256, 0, stream>>>(verts, trans, bmin, bmax);
  k_setup<<<1, 64, 0, stream>>>(bmin, bmax, center, inv_scale, validf, nv_acc,
                                jlist, jcount);
  k_phi<<<NP*16, 256, 0, stream>>>(verts, trans, center, inv_scale, phi);
  k_sample<<<dim3(7, NP), 1024, LDS_BYTES, stream>>>(verts, trans, center,
                                                     inv_scale, validf, phi,
                                                     jlist, jcount, nv_acc);
  k_final<<<1, 1, 0, stream>>>(nv_acc, out);
}

// Round 6
// 138.056 us; speedup vs baseline: 2.1796x; 1.0053x over previous
//
#include <hip/hip_runtime.h>

// SDFLoss: P=64 people, V=6890 verts, 32^3 SDF-band proxy grid, trilinear
// cross-sampling, scalar loss.
//
// phi stored as fp8(e4m3) x-PAIRS scaled by 64: entry[z][y][col] =
// (phi[x]*64, phi[x+1]*64), col = x0+1 (col 0 = x=-1 zero pad).
// k_soa pre-transposes verts to SoA with translation folded in, so k_sample's
// j-loop needs only 3 saddr dword loads + ~50 VALU per sample.

#define NP 64
#define NVERT 6890
#define GRD 32
#define ROWS 36                   // entries per (z,y) row
#define PLANE (GRD*ROWS + 2)      // 1154 entries per z-plane
#define PVOL (GRD*PLANE)          // 36928 entries per person (73856 B)
#define VSUB 256
#define VSTRIDE 26                // NVERT / VSUB
#define BAND 0.15f
#define PHI_SCALE 64.0f
#define INV_PHI_SCALE 0.015625f
#define LDS_BYTES (PVOL*2 + 64)

typedef float floatx2 __attribute__((ext_vector_type(2)));

__device__ __forceinline__ float wave_min(float v) {
  #pragma unroll
  for (int off = 32; off > 0; off >>= 1) v = fminf(v, __shfl_down(v, off));
  return v;
}
__device__ __forceinline__ float wave_max(float v) {
  #pragma unroll
  for (int off = 32; off > 0; off >>= 1) v = fmaxf(v, __shfl_down(v, off));
  return v;
}
__device__ __forceinline__ float wave_sum(float v) {
  #pragma unroll
  for (int off = 32; off > 0; off >>= 1) v += __shfl_down(v, off);
  return v;
}

// -------- kernel 0: SoA transpose with translation folded in --------
// vertsT[(j*3+c)*NVERT + v] = verts[j][v][c] + trans[j][c]
__global__ __launch_bounds__(256) void k_soa(
    const float* __restrict__ verts, const float* __restrict__ trans,
    float* __restrict__ vertsT) {
  int j = blockIdx.x;
  const float* vp = verts + (size_t)j * NVERT * 3;
  float t0 = trans[j*3+0], t1 = trans[j*3+1], t2 = trans[j*3+2];
  float* o0 = vertsT + (size_t)(j*3+0) * NVERT;
  float* o1 = vertsT + (size_t)(j*3+1) * NVERT;
  float* o2 = vertsT + (size_t)(j*3+2) * NVERT;
  for (int v = threadIdx.x; v < NVERT; v += 256) {
    o0[v] = vp[v*3+0] + t0;
    o1[v] = vp[v*3+1] + t1;
    o2[v] = vp[v*3+2] + t2;
  }
}

// -------- kernel 1: per-person bbox --------
__global__ __launch_bounds__(256) void k_bounds(
    const float* __restrict__ verts, const float* __restrict__ trans,
    float* __restrict__ bmin, float* __restrict__ bmax) {
  int p = blockIdx.x;
  const float* vp = verts + (size_t)p * NVERT * 3;
  float tx = trans[p*3+0], ty = trans[p*3+1], tz = trans[p*3+2];
  float mnx=1e30f, mny=1e30f, mnz=1e30f, mxx=-1e30f, mxy=-1e30f, mxz=-1e30f;
  for (int v = threadIdx.x; v < NVERT; v += blockDim.x) {
    float x = vp[v*3+0]+tx, y = vp[v*3+1]+ty, z = vp[v*3+2]+tz;
    mnx=fminf(mnx,x); mny=fminf(mny,y); mnz=fminf(mnz,z);
    mxx=fmaxf(mxx,x); mxy=fmaxf(mxy,y); mxz=fmaxf(mxz,z);
  }
  mnx=wave_min(mnx); mny=wave_min(mny); mnz=wave_min(mnz);
  mxx=wave_max(mxx); mxy=wave_max(mxy); mxz=wave_max(mxz);
  __shared__ float s[4][6];
  int wave = threadIdx.x >> 6, lane = threadIdx.x & 63;
  if (lane == 0) {
    s[wave][0]=mnx; s[wave][1]=mny; s[wave][2]=mnz;
    s[wave][3]=mxx; s[wave][4]=mxy; s[wave][5]=mxz;
  }
  __syncthreads();
  if (threadIdx.x == 0) {
    float a0=s[0][0],a1=s[0][1],a2=s[0][2],b0=s[0][3],b1=s[0][4],b2=s[0][5];
    for (int w = 1; w < 4; ++w) {
      a0=fminf(a0,s[w][0]); a1=fminf(a1,s[w][1]); a2=fminf(a2,s[w][2]);
      b0=fmaxf(b0,s[w][3]); b1=fmaxf(b1,s[w][4]); b2=fmaxf(b2,s[w][5]);
    }
    bmin[p*3+0]=a0; bmin[p*3+1]=a1; bmin[p*3+2]=a2;
    bmax[p*3+0]=b0; bmax[p*3+1]=b1; bmax[p*3+2]=b2;
  }
}

// -------- kernel 2: validity, center, inv_scale, nv, valid-j list --------
__global__ __launch_bounds__(64) void k_setup(
    const float* __restrict__ bmin, const float* __restrict__ bmax,
    float* __restrict__ center, float* __restrict__ inv_scale,
    float* __restrict__ validf, float* __restrict__ nv_acc,
    int* __restrict__ jlist, int* __restrict__ jcount) {
  __shared__ float smn[NP][3], smx[NP][3];
  int i = threadIdx.x;
  smn[i][0]=bmin[i*3+0]; smn[i][1]=bmin[i*3+1]; smn[i][2]=bmin[i*3+2];
  smx[i][0]=bmax[i*3+0]; smx[i][1]=bmax[i*3+1]; smx[i][2]=bmax[i*3+2];
  __syncthreads();
  bool valid = true;
  for (int j = 0; j < NP; ++j) {
    bool ov = true;
    #pragma unroll
    for (int c = 0; c < 3; ++c)
      ov = ov && (smn[i][c] <= smx[j][c]) && (smn[j][c] <= smx[i][c]);
    valid = valid && ov;
  }
  unsigned long long m = __ballot(valid);
  float nv = (float)__popcll(m);
  if (valid) {
    int pos = (int)__popcll(m & ((1ull << i) - 1ull));
    jlist[pos] = i;
  }
  float ext = fmaxf(smx[i][0]-smn[i][0], fmaxf(smx[i][1]-smn[i][1], smx[i][2]-smn[i][2]));
  float scale = 0.6f * ext;   // (1+0.2)*0.5 * max extent
  center[i*3+0] = 0.5f*(smn[i][0]+smx[i][0]);
  center[i*3+1] = 0.5f*(smn[i][1]+smx[i][1]);
  center[i*3+2] = 0.5f*(smn[i][2]+smx[i][2]);
  inv_scale[i] = 1.0f / scale;
  validf[i] = valid ? 1.0f : 0.0f;
  if (i == 0) {
    nv_acc[0] = nv; nv_acc[1] = 0.0f;
    jcount[0] = (int)__popcll(m);
  }
}

// -------- kernel 3: phi grid (fp8 x-pair layout, scaled x64) --------
__global__ __launch_bounds__(256) void k_phi(
    const float* __restrict__ verts, const float* __restrict__ trans,
    const float* __restrict__ center, const float* __restrict__ inv_scale,
    unsigned short* __restrict__ phi) {
  int p = blockIdx.x >> 4;
  int t = ((blockIdx.x & 15) << 8) + threadIdx.x;
  int x = t & 31, y = (t >> 5) & 31, zq = t >> 10;
  int lane = threadIdx.x & 63;

  __shared__ float sv[VSUB][3];
  {
    int k = threadIdx.x;
    int v = k * VSTRIDE;
    float cx = center[p*3+0], cy = center[p*3+1], cz = center[p*3+2];
    float is = inv_scale[p];
    const float* vp = verts + (size_t)p * NVERT * 3 + (size_t)v * 3;
    sv[k][0] = (vp[0] + trans[p*3+0] - cx) * is;
    sv[k][1] = (vp[1] + trans[p*3+1] - cy) * is;
    sv[k][2] = (vp[2] + trans[p*3+2] - cz) * is;
  }
  __syncthreads();

  const float inv = 1.0f / (float)GRD;
  float gx = (2.0f*x + 1.0f) * inv - 1.0f;
  float gy = (2.0f*y + 1.0f) * inv - 1.0f;
  float gz[8];
  #pragma unroll
  for (int k = 0; k < 8; ++k) gz[k] = (2.0f*(zq*8+k) + 1.0f) * inv - 1.0f;

  float d2[8];
  #pragma unroll
  for (int k = 0; k < 8; ++k) d2[k] = 1e30f;

  for (int v = 0; v < VSUB; ++v) {
    float dx = gx - sv[v][0];
    float dy = gy - sv[v][1];
    float vz = sv[v][2];
    float r2 = fmaf(dy, dy, dx*dx);
    #pragma unroll
    for (int k = 0; k < 8; ++k) {
      float dz = gz[k] - vz;
      d2[k] = fminf(d2[k], fmaf(dz, dz, r2));
    }
  }

  unsigned short* pp = phi + (size_t)p * PVOL;
  #pragma unroll
  for (int k = 0; k < 8; ++k) {
    float val = fmaxf(BAND - sqrtf(d2[k]), 0.0f) * PHI_SCALE;
    float nb = __shfl(val, (lane + 1) & 63);       // x+1 neighbor (same y-row)
    if (x == 31) nb = 0.0f;
    int z = zq*8 + k;
    int row = z*PLANE + y*ROWS;
    int pk = __builtin_amdgcn_cvt_pk_fp8_f32(val, nb, 0, false);
    pp[row + x + 1] = (unsigned short)(pk & 0xffff);
    if (x == 0) {
      int pk0 = __builtin_amdgcn_cvt_pk_fp8_f32(0.0f, val, 0, false);
      pp[row] = (unsigned short)(pk0 & 0xffff);
    }
  }
}

// -------- kernel 4: trilinear sample from LDS + reduce --------
__global__ __launch_bounds__(1024, 8) void k_sample(
    const float* __restrict__ vertsT, const float* __restrict__ center,
    const float* __restrict__ inv_scale, const float* __restrict__ validf,
    const unsigned short* __restrict__ phi, const int* __restrict__ jlist,
    const int* __restrict__ jcount, float* __restrict__ nv_acc) {
  extern __shared__ unsigned char smem[];
  unsigned short* sph = (unsigned short*)smem;
  float* red = (float*)(smem + (size_t)PVOL * 2);

  int i = blockIdx.y;
  if (validf[i] == 0.0f) return;
  int njl = jcount[0];

  // stage phi_i pair-volume into LDS (4616 uint4)
  {
    const uint4* src = (const uint4*)(phi + (size_t)i * PVOL);
    uint4* dst = (uint4*)smem;
    for (int t = threadIdx.x; t < PVOL/8; t += 1024) dst[t] = src[t];
  }
  __syncthreads();

  int v = blockIdx.x * 1024 + threadIdx.x;
  bool vok = v < NVERT;
  int vc = vok ? v : 0;
  float s16 = inv_scale[i] * 16.0f;
  // per-i scalar offsets; tail lanes get +1e9 so the bounds check rejects them
  float bix = fmaf(-center[i*3+0], s16, 15.5f) + (vok ? 0.0f : 1e9f);
  float biy = fmaf(-center[i*3+1], s16, 15.5f);
  float biz = fmaf(-center[i*3+2], s16, 15.5f);

  float acc = 0.0f;
  #pragma unroll 2
  for (int t = 0; t < njl; ++t) {
    int jj = jlist[t];                       // uniform -> scalar load/branch
    if (jj == i) continue;
    const float* bx = vertsT + (size_t)(jj*3) * NVERT;
    float X = fmaf(bx[vc],         s16, bix);
    float Y = fmaf(bx[NVERT+vc],   s16, biy);
    float Z = fmaf(bx[2*NVERT+vc], s16, biz);
    float xf = floorf(X), yf = floorf(Y), zf = floorf(Z);
    int x0 = (int)xf, y0 = (int)yf, z0 = (int)zf;
    if ((unsigned)(x0+1) <= 32u && (unsigned)(y0+1) <= 32u &&
        (unsigned)(z0+1) <= 32u) {
      float fx = X - xf, fy = Y - yf, fz = Z - zf;
      bool y0i = y0 >= 0,  y1i = y0 < 31;
      bool z0i = z0 >= 0,  z1i = z0 < 31;
      int yc0 = y0i ? y0 : 0;
      int zc0 = z0i ? z0 : 0;
      // base byte address of (zc0, yc0, col); neighbor offsets in bytes
      int a = (zc0*PLANE + yc0*ROWS + (x0+1)) * 2;
      int r1 = y1i ? ROWS*2  : 0;
      int p1 = z1i ? PLANE*2 : 0;
      floatx2 c00 = __builtin_amdgcn_cvt_pk_f32_fp8(
          (int)*(const unsigned short*)(smem + a), false);
      floatx2 c10 = __builtin_amdgcn_cvt_pk_f32_fp8(
          (int)*(const unsigned short*)(smem + a + r1), false);
      floatx2 c01 = __builtin_amdgcn_cvt_pk_f32_fp8(
          (int)*(const unsigned short*)(smem + a + p1), false);
      floatx2 c11 = __builtin_amdgcn_cvt_pk_f32_fp8(
          (int)*(const unsigned short*)(smem + a + p1 + r1), false);
      float a00 = fmaf(fx, c00.y - c00.x, c00.x);
      float a10 = fmaf(fx, c10.y - c10.x, c10.x);
      float a01 = fmaf(fx, c01.y - c01.x, c01.x);
      float a11 = fmaf(fx, c11.y - c11.x, c11.x);
      a00 = (y0i && z0i) ? a00 : 0.0f;
      a10 = (y1i && z0i) ? a10 : 0.0f;
      a01 = (y0i && z1i) ? a01 : 0.0f;
      a11 = (y1i && z1i) ? a11 : 0.0f;
      float b0 = fmaf(fy, a10 - a00, a00);
      float b1 = fmaf(fy, a11 - a01, a01);
      acc += fmaf(fz, b1 - b0, b0);
    }
  }

  acc = wave_sum(acc);
  int wave = threadIdx.x >> 6, lane = threadIdx.x & 63;
  if (lane == 0) red[wave] = acc;
  __syncthreads();
  if (threadIdx.x == 0) {
    float tot = 0.0f;
    #pragma unroll
    for (int w = 0; w < 16; ++w) tot += red[w];
    atomicAdd(&nv_acc[1], tot * INV_PHI_SCALE);
  }
}

// -------- kernel 5: finalize --------
__global__ void k_final(const float* __restrict__ nv_acc, float* __restrict__ out) {
  float nv = fmaxf(nv_acc[0], 1.0f);
  out[0] = nv_acc[1] / (nv * nv);
}

extern "C" void kernel_launch(void* const* d_in, const int* in_sizes, int n_in,
                              void* d_out, int out_size, void* d_ws, size_t ws_size,
                              hipStream_t stream) {
  const float* verts = (const float*)d_in[0];   // [64,6890,3]
  const float* trans = (const float*)d_in[1];   // [64,3]
  float* out = (float*)d_out;

  unsigned short* phi = (unsigned short*)d_ws;        // 64*36928*2 B = 4.73 MB
  float* vertsT    = (float*)((unsigned char*)d_ws + (size_t)NP * PVOL * 2);
  float* fb        = vertsT + (size_t)NP * 3 * NVERT; // SoA: 5.29 MB
  float* bmin      = fb;
  float* bmax      = bmin + NP*3;
  float* center    = bmax + NP*3;
  float* inv_scale = center + NP*3;
  float* validf    = inv_scale + NP;
  float* nv_acc    = validf + NP;                     // [0]=nv, [1]=loss acc
  int*   jlist     = (int*)(nv_acc + 2);
  int*   jcount    = jlist + NP;

  hipFuncSetAttribute((const void*)k_sample,
                      hipFuncAttributeMaxDynamicSharedMemorySize, LDS_BYTES);

  k_soa<<<NP, 256, 0, stream>>>(verts, trans, vertsT);
  k_bounds<<<NP, 256, 0, stream>>>(verts, trans, bmin, bmax);
  k_setup<<<1, 64, 0, stream>>>(bmin, bmax, center, inv_scale, validf, nv_acc,
                                jlist, jcount);
  k_phi<<<NP*16, 256, 0, stream>>>(verts, trans, center, inv_scale, phi);
  k_sample<<<dim3(7, NP), 1024, LDS_BYTES, stream>>>(vertsT, center, inv_scale,
                                                     validf, phi, jlist, jcount,
                                                     nv_acc);
  k_final<<<1, 1, 0, stream>>>(nv_acc, out);
}

// Round 7
// 132.678 us; speedup vs baseline: 2.2679x; 1.0405x over previous
//
#include <hip/hip_runtime.h>

// SDFLoss: P=64 people, V=6890 verts, 32^3 SDF-band proxy grid, trilinear
// cross-sampling, scalar loss.
//
// phi stored as a fully zero-padded QUAD volume: 32-bit word at (z,y,x)
// (indices 0..33 = grid -1..32) holds the 2x2 xy-patch as 4x fp8(e4m3),
// scaled x64: (phi[x,y], phi[x+1,y], phi[x,y+1], phi[x+1,y+1]) at plane z.
// Border words are zero, so trilinear sampling needs NO bounds logic:
// clamp, floor, 1 address, 2 ds_read_b32 (z and z+1), 4 cvt_pk, 15 FMAs.

#define NP 64
#define NVERT 6890
#define GRD 32
#define QDIM 34                   // -1..32 per axis
#define QPLANE (QDIM*QDIM)        // 1156 words
#define QVOL (QDIM*QPLANE)        // 39304 words = 157216 B
#define VSUB 256
#define VSTRIDE 26                // NVERT / VSUB
#define BAND 0.15f
#define PHI_SCALE 64.0f
#define INV_PHI_SCALE 0.015625f
#define LDS_BYTES (QVOL*4 + 64)

typedef float floatx2 __attribute__((ext_vector_type(2)));

__device__ __forceinline__ float wave_min(float v) {
  #pragma unroll
  for (int off = 32; off > 0; off >>= 1) v = fminf(v, __shfl_down(v, off));
  return v;
}
__device__ __forceinline__ float wave_max(float v) {
  #pragma unroll
  for (int off = 32; off > 0; off >>= 1) v = fmaxf(v, __shfl_down(v, off));
  return v;
}
__device__ __forceinline__ float wave_sum(float v) {
  #pragma unroll
  for (int off = 32; off > 0; off >>= 1) v += __shfl_down(v, off);
  return v;
}

// -------- kernel 1: fused SoA transpose (translation folded) + bbox --------
__global__ __launch_bounds__(256) void k_soa_bounds(
    const float* __restrict__ verts, const float* __restrict__ trans,
    float* __restrict__ vertsT, float* __restrict__ bmin,
    float* __restrict__ bmax) {
  int p = blockIdx.x;
  const float* vp = verts + (size_t)p * NVERT * 3;
  float tx = trans[p*3+0], ty = trans[p*3+1], tz = trans[p*3+2];
  float* o0 = vertsT + (size_t)(p*3+0) * NVERT;
  float* o1 = vertsT + (size_t)(p*3+1) * NVERT;
  float* o2 = vertsT + (size_t)(p*3+2) * NVERT;
  float mnx=1e30f, mny=1e30f, mnz=1e30f, mxx=-1e30f, mxy=-1e30f, mxz=-1e30f;
  for (int v = threadIdx.x; v < NVERT; v += blockDim.x) {
    float x = vp[v*3+0]+tx, y = vp[v*3+1]+ty, z = vp[v*3+2]+tz;
    o0[v] = x; o1[v] = y; o2[v] = z;
    mnx=fminf(mnx,x); mny=fminf(mny,y); mnz=fminf(mnz,z);
    mxx=fmaxf(mxx,x); mxy=fmaxf(mxy,y); mxz=fmaxf(mxz,z);
  }
  mnx=wave_min(mnx); mny=wave_min(mny); mnz=wave_min(mnz);
  mxx=wave_max(mxx); mxy=wave_max(mxy); mxz=wave_max(mxz);
  __shared__ float s[4][6];
  int wave = threadIdx.x >> 6, lane = threadIdx.x & 63;
  if (lane == 0) {
    s[wave][0]=mnx; s[wave][1]=mny; s[wave][2]=mnz;
    s[wave][3]=mxx; s[wave][4]=mxy; s[wave][5]=mxz;
  }
  __syncthreads();
  if (threadIdx.x == 0) {
    float a0=s[0][0],a1=s[0][1],a2=s[0][2],b0=s[0][3],b1=s[0][4],b2=s[0][5];
    for (int w = 1; w < 4; ++w) {
      a0=fminf(a0,s[w][0]); a1=fminf(a1,s[w][1]); a2=fminf(a2,s[w][2]);
      b0=fmaxf(b0,s[w][3]); b1=fmaxf(b1,s[w][4]); b2=fmaxf(b2,s[w][5]);
    }
    bmin[p*3+0]=a0; bmin[p*3+1]=a1; bmin[p*3+2]=a2;
    bmax[p*3+0]=b0; bmax[p*3+1]=b1; bmax[p*3+2]=b2;
  }
}

// -------- kernel 2: validity, center, inv_scale, nv, valid-j list --------
__global__ __launch_bounds__(64) void k_setup(
    const float* __restrict__ bmin, const float* __restrict__ bmax,
    float* __restrict__ center, float* __restrict__ inv_scale,
    float* __restrict__ validf, float* __restrict__ nv_acc,
    int* __restrict__ jlist, int* __restrict__ jcount) {
  __shared__ float smn[NP][3], smx[NP][3];
  int i = threadIdx.x;
  smn[i][0]=bmin[i*3+0]; smn[i][1]=bmin[i*3+1]; smn[i][2]=bmin[i*3+2];
  smx[i][0]=bmax[i*3+0]; smx[i][1]=bmax[i*3+1]; smx[i][2]=bmax[i*3+2];
  __syncthreads();
  bool valid = true;
  for (int j = 0; j < NP; ++j) {
    bool ov = true;
    #pragma unroll
    for (int c = 0; c < 3; ++c)
      ov = ov && (smn[i][c] <= smx[j][c]) && (smn[j][c] <= smx[i][c]);
    valid = valid && ov;
  }
  unsigned long long m = __ballot(valid);
  float nv = (float)__popcll(m);
  if (valid) {
    int pos = (int)__popcll(m & ((1ull << i) - 1ull));
    jlist[pos] = i;
  }
  float ext = fmaxf(smx[i][0]-smn[i][0], fmaxf(smx[i][1]-smn[i][1], smx[i][2]-smn[i][2]));
  float scale = 0.6f * ext;   // (1+0.2)*0.5 * max extent
  center[i*3+0] = 0.5f*(smn[i][0]+smx[i][0]);
  center[i*3+1] = 0.5f*(smn[i][1]+smx[i][1]);
  center[i*3+2] = 0.5f*(smn[i][2]+smx[i][2]);
  inv_scale[i] = 1.0f / scale;
  validf[i] = valid ? 1.0f : 0.0f;
  if (i == 0) {
    nv_acc[0] = nv; nv_acc[1] = 0.0f;
    jcount[0] = (int)__popcll(m);
  }
}

// -------- kernel 3: phi grid -> fp8 quad volume --------
// block = 1024 threads = one full 32x32 xy-plane set; 4 z-slabs of 8 per person.
__global__ __launch_bounds__(1024) void k_phi(
    const float* __restrict__ verts, const float* __restrict__ trans,
    const float* __restrict__ center, const float* __restrict__ inv_scale,
    unsigned int* __restrict__ quad) {
  int p = blockIdx.x >> 2;
  int zq = blockIdx.x & 3;
  int tid = threadIdx.x;
  int x = tid & 31, y = tid >> 5;

  __shared__ float sv[VSUB][3];
  __shared__ float phib[8][32][32];   // 32 KB

  if (tid < VSUB) {
    int v = tid * VSTRIDE;
    float cx = center[p*3+0], cy = center[p*3+1], cz = center[p*3+2];
    float is = inv_scale[p];
    const float* vp = verts + (size_t)p * NVERT * 3 + (size_t)v * 3;
    sv[tid][0] = (vp[0] + trans[p*3+0] - cx) * is;
    sv[tid][1] = (vp[1] + trans[p*3+1] - cy) * is;
    sv[tid][2] = (vp[2] + trans[p*3+2] - cz) * is;
  }
  __syncthreads();

  const float inv = 1.0f / (float)GRD;
  float gx = (2.0f*x + 1.0f) * inv - 1.0f;
  float gy = (2.0f*y + 1.0f) * inv - 1.0f;
  float gz[8];
  #pragma unroll
  for (int k = 0; k < 8; ++k) gz[k] = (2.0f*(zq*8+k) + 1.0f) * inv - 1.0f;

  float d2[8];
  #pragma unroll
  for (int k = 0; k < 8; ++k) d2[k] = 1e30f;

  for (int v = 0; v < VSUB; ++v) {
    float dx = gx - sv[v][0];
    float dy = gy - sv[v][1];
    float vz = sv[v][2];
    float r2 = fmaf(dy, dy, dx*dx);
    #pragma unroll
    for (int k = 0; k < 8; ++k) {
      float dz = gz[k] - vz;
      d2[k] = fminf(d2[k], fmaf(dz, dz, r2));
    }
  }
  #pragma unroll
  for (int k = 0; k < 8; ++k)
    phib[k][y][x] = fmaxf(BAND - sqrtf(d2[k]), 0.0f) * PHI_SCALE;
  __syncthreads();

  // quad assembly: word(qz, qy, qx) for qx,qy in [-1,32]
  unsigned int* qp = quad + (size_t)p * QVOL;
  for (int idx = tid; idx < QPLANE; idx += 1024) {
    int qy = idx / QDIM - 1, qx = idx % QDIM - 1;
    bool x0ok = (unsigned)qx < 32u, x1ok = (unsigned)(qx+1) < 32u;
    bool y0ok = (unsigned)qy < 32u, y1ok = (unsigned)(qy+1) < 32u;
    int xc0 = x0ok ? qx : 0, xc1 = x1ok ? qx+1 : 0;
    int yc0 = y0ok ? qy : 0, yc1 = y1ok ? qy+1 : 0;
    #pragma unroll
    for (int k = 0; k < 8; ++k) {
      float a = (x0ok && y0ok) ? phib[k][yc0][xc0] : 0.0f;
      float b = (x1ok && y0ok) ? phib[k][yc0][xc1] : 0.0f;
      float c = (x0ok && y1ok) ? phib[k][yc1][xc0] : 0.0f;
      float d = (x1ok && y1ok) ? phib[k][yc1][xc1] : 0.0f;
      int lo = __builtin_amdgcn_cvt_pk_fp8_f32(a, b, 0, false);
      int w  = __builtin_amdgcn_cvt_pk_fp8_f32(c, d, lo, true);
      qp[(zq*8 + k + 1)*QPLANE + idx] = (unsigned int)w;
    }
    if (zq == 0) qp[idx] = 0u;                  // plane 0  (z = -1): zeros
    if (zq == 3) qp[33*QPLANE + idx] = 0u;      // plane 33 (z = 32): zeros
  }
}

// -------- trilinear sample from the LDS quad volume --------
__device__ __forceinline__ float qsample(const unsigned char* sq,
                                         float X, float Y, float Z) {
  // coords are pre-offset by +1 (volume index space 0..33)
  X = fminf(fmaxf(X, 0.0f), 33.99f);
  Y = fminf(fmaxf(Y, 0.0f), 33.99f);
  Z = fminf(fmaxf(Z, 0.0f), 32.999f);   // z0<=32: planes 32,33 (33 = zeros)
  float xf = floorf(X), yf = floorf(Y), zf = floorf(Z);
  float fx = X - xf, fy = Y - yf, fz = Z - zf;
  int e = ((int)zf * QDIM + (int)yf) * QDIM + (int)xf;
  unsigned int w0 = *(const unsigned int*)(sq + e*4);
  unsigned int w1 = *(const unsigned int*)(sq + e*4 + QPLANE*4);
  floatx2 l0 = __builtin_amdgcn_cvt_pk_f32_fp8((int)w0, false);
  floatx2 h0 = __builtin_amdgcn_cvt_pk_f32_fp8((int)w0, true);
  floatx2 l1 = __builtin_amdgcn_cvt_pk_f32_fp8((int)w1, false);
  floatx2 h1 = __builtin_amdgcn_cvt_pk_f32_fp8((int)w1, true);
  float u0 = fmaf(fx, l0.y - l0.x, l0.x);
  float u1 = fmaf(fx, h0.y - h0.x, h0.x);
  float vA = fmaf(fy, u1 - u0, u0);
  float u2 = fmaf(fx, l1.y - l1.x, l1.x);
  float u3 = fmaf(fx, h1.y - h1.x, h1.x);
  float vB = fmaf(fy, u3 - u2, u2);
  return fmaf(fz, vB - vA, vA);
}

// -------- kernel 4: sample + reduce. 896 thr, 2 vert slots/thread, 1 blk/CU --------
__global__ __launch_bounds__(896) void k_sample(
    const float* __restrict__ vertsT, const float* __restrict__ center,
    const float* __restrict__ inv_scale, const float* __restrict__ validf,
    const unsigned int* __restrict__ quad, const int* __restrict__ jlist,
    const int* __restrict__ jcount, float* __restrict__ nv_acc) {
  extern __shared__ unsigned char smem[];
  float* red = (float*)(smem + (size_t)QVOL * 4);

  int i = blockIdx.y;
  if (validf[i] == 0.0f) return;
  int njl = jcount[0];

  // stage quad volume (157216 B = 9826 uint4) into LDS
  {
    const uint4* src = (const uint4*)(quad + (size_t)i * QVOL);
    uint4* dst = (uint4*)smem;
    for (int t = threadIdx.x; t < QVOL/4; t += 896) dst[t] = src[t];
  }
  __syncthreads();

  int v0 = blockIdx.x * 1792 + threadIdx.x;   // always < NVERT (max 6271)
  int v1 = v0 + 896;
  bool ok1 = v1 < NVERT;
  int vc1 = ok1 ? v1 : 0;

  float s16 = inv_scale[i] * 16.0f;
  // +1 volume-index offset folded: 15.5 + 1 = 16.5
  float bx = fmaf(-center[i*3+0], s16, 16.5f);
  float by = fmaf(-center[i*3+1], s16, 16.5f);
  float bz = fmaf(-center[i*3+2], s16, 16.5f);
  float bx1 = bx + (ok1 ? 0.0f : 1e9f);       // dead slot -> clamps to zero words

  float acc = 0.0f;
  #pragma unroll 2
  for (int t = 0; t < njl; ++t) {
    int jj = jlist[t];                         // uniform scalar
    if (jj == i) continue;
    const float* p0 = vertsT + (size_t)(jj*3) * NVERT;
    float X0 = fmaf(p0[v0],          s16, bx);
    float Y0 = fmaf(p0[NVERT+v0],    s16, by);
    float Z0 = fmaf(p0[2*NVERT+v0],  s16, bz);
    float X1 = fmaf(p0[vc1],         s16, bx1);
    float Y1 = fmaf(p0[NVERT+vc1],   s16, by);
    float Z1 = fmaf(p0[2*NVERT+vc1], s16, bz);
    acc += qsample(smem, X0, Y0, Z0);
    acc += qsample(smem, X1, Y1, Z1);
  }

  acc = wave_sum(acc);
  int wave = threadIdx.x >> 6, lane = threadIdx.x & 63;
  if (lane == 0) red[wave] = acc;
  __syncthreads();
  if (threadIdx.x == 0) {
    float tot = 0.0f;
    #pragma unroll
    for (int w = 0; w < 14; ++w) tot += red[w];
    atomicAdd(&nv_acc[1], tot * INV_PHI_SCALE);
  }
}

// -------- kernel 5: finalize --------
__global__ void k_final(const float* __restrict__ nv_acc, float* __restrict__ out) {
  float nv = fmaxf(nv_acc[0], 1.0f);
  out[0] = nv_acc[1] / (nv * nv);
}

extern "C" void kernel_launch(void* const* d_in, const int* in_sizes, int n_in,
                              void* d_out, int out_size, void* d_ws, size_t ws_size,
                              hipStream_t stream) {
  const float* verts = (const float*)d_in[0];   // [64,6890,3]
  const float* trans = (const float*)d_in[1];   // [64,3]
  float* out = (float*)d_out;

  unsigned int* quad = (unsigned int*)d_ws;           // 64*39304*4 B = 10.06 MB
  float* vertsT    = (float*)d_ws + (size_t)NP * QVOL;
  float* fb        = vertsT + (size_t)NP * 3 * NVERT; // SoA: 5.29 MB
  float* bmin      = fb;
  float* bmax      = bmin + NP*3;
  float* center    = bmax + NP*3;
  float* inv_scale = center + NP*3;
  float* validf    = inv_scale + NP;
  float* nv_acc    = validf + NP;                     // [0]=nv, [1]=loss acc
  int*   jlist     = (int*)(nv_acc + 2);
  int*   jcount    = jlist + NP;

  hipFuncSetAttribute((const void*)k_sample,
                      hipFuncAttributeMaxDynamicSharedMemorySize, LDS_BYTES);

  k_soa_bounds<<<NP, 256, 0, stream>>>(verts, trans, vertsT, bmin, bmax);
  k_setup<<<1, 64, 0, stream>>>(bmin, bmax, center, inv_scale, validf, nv_acc,
                                jlist, jcount);
  k_phi<<<NP*4, 1024, 0, stream>>>(verts, trans, center, inv_scale, quad);
  k_sample<<<dim3(4, NP), 896, LDS_BYTES, stream>>>(vertsT, center, inv_scale,
                                                    validf, quad, jlist, jcount,
                                                    nv_acc);
  k_final<<<1, 1, 0, stream>>>(nv_acc, out);
}

// Round 10
// 120.206 us; speedup vs baseline: 2.5032x; 1.1038x over previous
//
#include <hip/hip_runtime.h>

// SDFLoss: P=64 people, V=6890 verts, 32^3 SDF-band proxy grid, trilinear
// cross-sampling, scalar loss.
//
// phi stored as a fully zero-padded PAIR volume: u16 at (iz,iy,ix),
// indices 0..33 = grid -1..32, holding (phi[gx], phi[gx+1]) as 2x fp8(e4m3)
// scaled x64 (gx = ix-1, row gy = iy-1, plane gz = iz-1; OOB -> 0).
// 34^3 x 2B = 78,608 B -> 2 blocks/CU in k_sample (28 waves/CU).
// Sampling: clamp, floor, 1 address, 4 ds_read_u16 (imm offsets), 4 cvt_pk,
// ~15 FMAs. No bounds logic (borders are zero data).

#define NP 64
#define NVERT 6890
#define GRD 32
#define QDIM 34                   // -1..32 per axis
#define QPLANE (QDIM*QDIM)        // 1156 entries
#define QVOL (QDIM*QPLANE)        // 39304 entries = 78608 B
#define VSUB 256
#define VSTRIDE 26                // NVERT / VSUB
#define BAND 0.15f
#define PHI_SCALE 64.0f
#define INV_PHI_SCALE 0.015625f
#define LDS_BYTES (QVOL*2 + 64)

typedef float floatx2 __attribute__((ext_vector_type(2)));

__device__ __forceinline__ float wave_min(float v) {
  #pragma unroll
  for (int off = 32; off > 0; off >>= 1) v = fminf(v, __shfl_down(v, off));
  return v;
}
__device__ __forceinline__ float wave_max(float v) {
  #pragma unroll
  for (int off = 32; off > 0; off >>= 1) v = fmaxf(v, __shfl_down(v, off));
  return v;
}
__device__ __forceinline__ float wave_sum(float v) {
  #pragma unroll
  for (int off = 32; off > 0; off >>= 1) v += __shfl_down(v, off);
  return v;
}

// -------- kernel 1: fused SoA transpose (translation folded) + bbox --------
__global__ __launch_bounds__(256) void k_soa_bounds(
    const float* __restrict__ verts, const float* __restrict__ trans,
    float* __restrict__ vertsT, float* __restrict__ bmin,
    float* __restrict__ bmax) {
  int p = blockIdx.x;
  const float* vp = verts + (size_t)p * NVERT * 3;
  float tx = trans[p*3+0], ty = trans[p*3+1], tz = trans[p*3+2];
  float* o0 = vertsT + (size_t)(p*3+0) * NVERT;
  float* o1 = vertsT + (size_t)(p*3+1) * NVERT;
  float* o2 = vertsT + (size_t)(p*3+2) * NVERT;
  float mnx=1e30f, mny=1e30f, mnz=1e30f, mxx=-1e30f, mxy=-1e30f, mxz=-1e30f;
  for (int v = threadIdx.x; v < NVERT; v += blockDim.x) {
    float x = vp[v*3+0]+tx, y = vp[v*3+1]+ty, z = vp[v*3+2]+tz;
    o0[v] = x; o1[v] = y; o2[v] = z;
    mnx=fminf(mnx,x); mny=fminf(mny,y); mnz=fminf(mnz,z);
    mxx=fmaxf(mxx,x); mxy=fmaxf(mxy,y); mxz=fmaxf(mxz,z);
  }
  mnx=wave_min(mnx); mny=wave_min(mny); mnz=wave_min(mnz);
  mxx=wave_max(mxx); mxy=wave_max(mxy); mxz=wave_max(mxz);
  __shared__ float s[4][6];
  int wave = threadIdx.x >> 6, lane = threadIdx.x & 63;
  if (lane == 0) {
    s[wave][0]=mnx; s[wave][1]=mny; s[wave][2]=mnz;
    s[wave][3]=mxx; s[wave][4]=mxy; s[wave][5]=mxz;
  }
  __syncthreads();
  if (threadIdx.x == 0) {
    float a0=s[0][0],a1=s[0][1],a2=s[0][2],b0=s[0][3],b1=s[0][4],b2=s[0][5];
    for (int w = 1; w < 4; ++w) {
      a0=fminf(a0,s[w][0]); a1=fminf(a1,s[w][1]); a2=fminf(a2,s[w][2]);
      b0=fmaxf(b0,s[w][3]); b1=fmaxf(b1,s[w][4]); b2=fmaxf(b2,s[w][5]);
    }
    bmin[p*3+0]=a0; bmin[p*3+1]=a1; bmin[p*3+2]=a2;
    bmax[p*3+0]=b0; bmax[p*3+1]=b1; bmax[p*3+2]=b2;
  }
}

// -------- kernel 2: validity, center, inv_scale, nv, valid-j list --------
__global__ __launch_bounds__(64) void k_setup(
    const float* __restrict__ bmin, const float* __restrict__ bmax,
    float* __restrict__ center, float* __restrict__ inv_scale,
    float* __restrict__ validf, float* __restrict__ nv_acc,
    int* __restrict__ jlist, int* __restrict__ jcount) {
  __shared__ float smn[NP][3], smx[NP][3];
  int i = threadIdx.x;
  smn[i][0]=bmin[i*3+0]; smn[i][1]=bmin[i*3+1]; smn[i][2]=bmin[i*3+2];
  smx[i][0]=bmax[i*3+0]; smx[i][1]=bmax[i*3+1]; smx[i][2]=bmax[i*3+2];
  __syncthreads();
  bool valid = true;
  for (int j = 0; j < NP; ++j) {
    bool ov = true;
    #pragma unroll
    for (int c = 0; c < 3; ++c)
      ov = ov && (smn[i][c] <= smx[j][c]) && (smn[j][c] <= smx[i][c]);
    valid = valid && ov;
  }
  unsigned long long m = __ballot(valid);
  float nv = (float)__popcll(m);
  if (valid) {
    int pos = (int)__popcll(m & ((1ull << i) - 1ull));
    jlist[pos] = i;
  }
  float ext = fmaxf(smx[i][0]-smn[i][0], fmaxf(smx[i][1]-smn[i][1], smx[i][2]-smn[i][2]));
  float scale = 0.6f * ext;   // (1+0.2)*0.5 * max extent
  center[i*3+0] = 0.5f*(smn[i][0]+smx[i][0]);
  center[i*3+1] = 0.5f*(smn[i][1]+smx[i][1]);
  center[i*3+2] = 0.5f*(smn[i][2]+smx[i][2]);
  inv_scale[i] = 1.0f / scale;
  validf[i] = valid ? 1.0f : 0.0f;
  if (i == 0) {
    nv_acc[0] = nv; nv_acc[1] = 0.0f;
    jcount[0] = (int)__popcll(m);
  }
}

// -------- kernel 3: phi grid -> fp8 pair volume, with z-slab vert culling ----
// block = 1024 threads (32x32 xy); 4 z-slabs of 8 planes per person.
__global__ __launch_bounds__(1024) void k_phi(
    const float* __restrict__ verts, const float* __restrict__ trans,
    const float* __restrict__ center, const float* __restrict__ inv_scale,
    unsigned short* __restrict__ pairs) {
  int p = blockIdx.x >> 2;
  int zq = blockIdx.x & 3;
  int tid = threadIdx.x;
  int x = tid & 31, y = tid >> 5;

  __shared__ float kv[VSUB][3];       // culled vertex list
  __shared__ float phib[8][32][32];   // 32 KB
  __shared__ int nkeep;

  const float inv = 1.0f / (float)GRD;
  if (tid == 0) nkeep = 0;
  __syncthreads();

  // load + z-slab cull: vertex can only matter if its z-distance to the
  // slab's cell-center range is < BAND (d^2 >= dz^2).
  if (tid < VSUB) {
    int v = tid * VSTRIDE;
    float cx = center[p*3+0], cy = center[p*3+1], cz = center[p*3+2];
    float is = inv_scale[p];
    const float* vp = verts + (size_t)p * NVERT * 3 + (size_t)v * 3;
    float X = (vp[0] + trans[p*3+0] - cx) * is;
    float Y = (vp[1] + trans[p*3+1] - cy) * is;
    float Z = (vp[2] + trans[p*3+2] - cz) * is;
    float zlo = (2.0f*(zq*8)     + 1.0f) * inv - 1.0f;
    float zhi = (2.0f*(zq*8 + 7) + 1.0f) * inv - 1.0f;
    float dz = fmaxf(fmaxf(zlo - Z, Z - zhi), 0.0f);
    if (dz < BAND) {
      int idx = atomicAdd(&nkeep, 1);
      kv[idx][0] = X; kv[idx][1] = Y; kv[idx][2] = Z;
    }
  }
  __syncthreads();
  int nk = nkeep;

  float gx = (2.0f*x + 1.0f) * inv - 1.0f;
  float gy = (2.0f*y + 1.0f) * inv - 1.0f;
  float gz[8];
  #pragma unroll
  for (int k = 0; k < 8; ++k) gz[k] = (2.0f*(zq*8+k) + 1.0f) * inv - 1.0f;

  float d2[8];
  #pragma unroll
  for (int k = 0; k < 8; ++k) d2[k] = 1e30f;

  for (int v = 0; v < nk; ++v) {
    float dx = gx - kv[v][0];
    float dy = gy - kv[v][1];
    float vz = kv[v][2];
    float r2 = fmaf(dy, dy, dx*dx);
    #pragma unroll
    for (int k = 0; k < 8; ++k) {
      float dz = gz[k] - vz;
      d2[k] = fminf(d2[k], fmaf(dz, dz, r2));
    }
  }
  #pragma unroll
  for (int k = 0; k < 8; ++k)
    phib[k][y][x] = fmaxf(BAND - sqrtf(d2[k]), 0.0f) * PHI_SCALE;
  __syncthreads();

  // pair assembly: u16 at (iz, iy, ix); gy = iy-1, gx = ix-1
  unsigned short* qp = pairs + (size_t)p * QVOL;
  for (int idx = tid; idx < QPLANE; idx += 1024) {
    int iy = idx / QDIM, ix = idx % QDIM;
    int gyy = iy - 1, gxx = ix - 1;
    bool gyok = (unsigned)gyy < 32u;
    bool aok = gyok && ((unsigned)gxx < 32u);
    bool bok = gyok && ((unsigned)ix  < 32u);
    int ya = gyok ? gyy : 0;
    int xa = aok ? gxx : 0;
    int xb = bok ? ix : 0;
    #pragma unroll
    for (int k = 0; k < 8; ++k) {
      float a = aok ? phib[k][ya][xa] : 0.0f;
      float b = bok ? phib[k][ya][xb] : 0.0f;
      int pk = __builtin_amdgcn_cvt_pk_fp8_f32(a, b, 0, false);
      qp[(zq*8 + k + 1)*QPLANE + idx] = (unsigned short)(pk & 0xffff);
    }
    if (zq == 0) qp[idx] = 0;                  // plane 0  (gz = -1)
    if (zq == 3) qp[33*QPLANE + idx] = 0;      // plane 33 (gz = 32)
  }
}

// -------- trilinear sample from the LDS pair volume --------
__device__ __forceinline__ float qsample(const unsigned short* q,
                                         float X, float Y, float Z) {
  // coords pre-offset by +1 (volume index space)
  X = fminf(fmaxf(X, 0.0f), 33.99f);
  Y = fminf(fmaxf(Y, 0.0f), 32.999f);
  Z = fminf(fmaxf(Z, 0.0f), 32.999f);
  float xf = floorf(X), yf = floorf(Y), zf = floorf(Z);
  float fx = X - xf, fy = Y - yf, fz = Z - zf;
  int e = ((int)zf * QDIM + (int)yf) * QDIM + (int)xf;
  unsigned int w00 = q[e];
  unsigned int w10 = q[e + QDIM];
  unsigned int w01 = q[e + QPLANE];
  unsigned int w11 = q[e + QPLANE + QDIM];
  floatx2 c00 = __builtin_amdgcn_cvt_pk_f32_fp8((int)w00, false);
  floatx2 c10 = __builtin_amdgcn_cvt_pk_f32_fp8((int)w10, false);
  floatx2 c01 = __builtin_amdgcn_cvt_pk_f32_fp8((int)w01, false);
  floatx2 c11 = __builtin_amdgcn_cvt_pk_f32_fp8((int)w11, false);
  float u00 = fmaf(fx, c00.y - c00.x, c00.x);
  float u10 = fmaf(fx, c10.y - c10.x, c10.x);
  float u01 = fmaf(fx, c01.y - c01.x, c01.x);
  float u11 = fmaf(fx, c11.y - c11.x, c11.x);
  float a0 = fmaf(fy, u10 - u00, u00);
  float a1 = fmaf(fy, u11 - u01, u01);
  return fmaf(fz, a1 - a0, a0);
}

// -------- kernel 4: sample + reduce. 896 thr, 1 slot/thread, 2 blk/CU --------
__global__ __launch_bounds__(896, 7) void k_sample(
    const float* __restrict__ vertsT, const float* __restrict__ center,
    const float* __restrict__ inv_scale, const float* __restrict__ validf,
    const unsigned short* __restrict__ pairs, const int* __restrict__ jlist,
    const int* __restrict__ jcount, float* __restrict__ nv_acc) {
  extern __shared__ unsigned char smem[];
  const unsigned short* sq = (const unsigned short*)smem;
  float* red = (float*)(smem + (size_t)QVOL * 2);

  int i = blockIdx.y;
  if (validf[i] == 0.0f) return;
  int njl = jcount[0];

  // stage pair volume (78608 B = 4913 uint4) into LDS
  {
    const uint4* src = (const uint4*)(pairs + (size_t)i * QVOL);
    uint4* dst = (uint4*)smem;
    for (int t = threadIdx.x; t < QVOL/8; t += 896) dst[t] = src[t];
  }
  __syncthreads();

  int v = blockIdx.x * 896 + threadIdx.x;
  bool ok = v < NVERT;
  int vc = ok ? v : 0;

  float s16 = inv_scale[i] * 16.0f;
  // +1 volume-index offset folded: 15.5 + 1 = 16.5
  float bx = fmaf(-center[i*3+0], s16, 16.5f) + (ok ? 0.0f : 1e9f);
  float by = fmaf(-center[i*3+1], s16, 16.5f);
  float bz = fmaf(-center[i*3+2], s16, 16.5f);

  float acc = 0.0f;
  #pragma unroll 2
  for (int t = 0; t < njl; ++t) {
    int jj = jlist[t];                         // uniform scalar
    if (jj == i) continue;
    const float* p0 = vertsT + (size_t)(jj*3) * NVERT;
    float X = fmaf(p0[vc],         s16, bx);
    float Y = fmaf(p0[NVERT+vc],   s16, by);
    float Z = fmaf(p0[2*NVERT+vc], s16, bz);
    acc += qsample(sq, X, Y, Z);
  }

  acc = wave_sum(acc);
  int wave = threadIdx.x >> 6, lane = threadIdx.x & 63;
  if (lane == 0) red[wave] = acc;
  __syncthreads();
  if (threadIdx.x == 0) {
    float tot = 0.0f;
    #pragma unroll
    for (int w = 0; w < 14; ++w) tot += red[w];
    atomicAdd(&nv_acc[1], tot * INV_PHI_SCALE);
  }
}

// -------- kernel 5: finalize --------
__global__ void k_final(const float* __restrict__ nv_acc, float* __restrict__ out) {
  float nv = fmaxf(nv_acc[0], 1.0f);
  out[0] = nv_acc[1] / (nv * nv);
}

extern "C" void kernel_launch(void* const* d_in, const int* in_sizes, int n_in,
                              void* d_out, int out_size, void* d_ws, size_t ws_size,
                              hipStream_t stream) {
  const float* verts = (const float*)d_in[0];   // [64,6890,3]
  const float* trans = (const float*)d_in[1];   // [64,3]
  float* out = (float*)d_out;

  unsigned short* pairs = (unsigned short*)d_ws;      // 64*39304*2 B = 5.03 MB
  float* vertsT    = (float*)((unsigned char*)d_ws + (size_t)NP * QVOL * 2);
  float* fb        = vertsT + (size_t)NP * 3 * NVERT; // SoA: 5.29 MB
  float* bmin      = fb;
  float* bmax      = bmin + NP*3;
  float* center    = bmax + NP*3;
  float* inv_scale = center + NP*3;
  float* validf    = inv_scale + NP;
  float* nv_acc    = validf + NP;                     // [0]=nv, [1]=loss acc
  int*   jlist     = (int*)(nv_acc + 2);
  int*   jcount    = jlist + NP;

  hipFuncSetAttribute((const void*)k_sample,
                      hipFuncAttributeMaxDynamicSharedMemorySize, LDS_BYTES);

  k_soa_bounds<<<NP, 256, 0, stream>>>(verts, trans, vertsT, bmin, bmax);
  k_setup<<<1, 64, 0, stream>>>(bmin, bmax, center, inv_scale, validf, nv_acc,
                                jlist, jcount);
  k_phi<<<NP*4, 1024, 0, stream>>>(verts, trans, center, inv_scale, pairs);
  k_sample<<<dim3(8, NP), 896, LDS_BYTES, stream>>>(vertsT, center, inv_scale,
                                                    validf, pairs, jlist, jcount,
                                                    nv_acc);
  k_final<<<1, 1, 0, stream>>>(nv_acc, out);
}

// Round 11
// 119.312 us; speedup vs baseline: 2.5220x; 1.0075x over previous
//
#include <hip/hip_runtime.h>

// SDFLoss: P=64 people, V=6890 verts, 32^3 SDF-band proxy grid, trilinear
// cross-sampling, scalar loss.
//
// 3 kernels: k_soa_bounds (SoA + bbox + zero accumulators), k_phi (fp8 pair
// volume, z-slab + per-wave y-row culling), k_sample (validity mask inline,
// LDS-staged pair volume, trilinear, last-block finalize).
//
// phi: fully zero-padded PAIR volume, u16 at (iz,iy,ix), idx 0..33 = grid
// -1..32, holding (phi[gx], phi[gx+1]) as 2x fp8(e4m3) scaled x64.
// 34^3 x 2B = 78,608 B -> 2 blocks/CU in k_sample.

#define NP 64
#define NVERT 6890
#define GRD 32
#define QDIM 34                   // -1..32 per axis
#define QPLANE (QDIM*QDIM)        // 1156 entries
#define QVOL (QDIM*QPLANE)        // 39304 entries = 78608 B
#define VSUB 256
#define VSTRIDE 26                // NVERT / VSUB
#define BAND 0.15f
#define PHI_SCALE 64.0f
#define INV_PHI_SCALE 0.015625f
#define LDS_BYTES (QVOL*2 + 128)
#define SAMPLE_BLOCKS (8*NP)

typedef float floatx2 __attribute__((ext_vector_type(2)));

__device__ __forceinline__ float wave_min(float v) {
  #pragma unroll
  for (int off = 32; off > 0; off >>= 1) v = fminf(v, __shfl_down(v, off));
  return v;
}
__device__ __forceinline__ float wave_max(float v) {
  #pragma unroll
  for (int off = 32; off > 0; off >>= 1) v = fmaxf(v, __shfl_down(v, off));
  return v;
}
__device__ __forceinline__ float wave_sum(float v) {
  #pragma unroll
  for (int off = 32; off > 0; off >>= 1) v += __shfl_down(v, off);
  return v;
}

// -------- kernel 1: SoA transpose (translation folded) + bbox + zero accs ----
__global__ __launch_bounds__(256) void k_soa_bounds(
    const float* __restrict__ verts, const float* __restrict__ trans,
    float* __restrict__ vertsT, float* __restrict__ bbox,
    float* __restrict__ accp, unsigned int* __restrict__ donep) {
  int p = blockIdx.x;
  if (p == 0 && threadIdx.x == 0) { accp[0] = 0.0f; donep[0] = 0u; }
  const float* vp = verts + (size_t)p * NVERT * 3;
  float tx = trans[p*3+0], ty = trans[p*3+1], tz = trans[p*3+2];
  float* o0 = vertsT + (size_t)(p*3+0) * NVERT;
  float* o1 = vertsT + (size_t)(p*3+1) * NVERT;
  float* o2 = vertsT + (size_t)(p*3+2) * NVERT;
  float mnx=1e30f, mny=1e30f, mnz=1e30f, mxx=-1e30f, mxy=-1e30f, mxz=-1e30f;
  for (int v = threadIdx.x; v < NVERT; v += blockDim.x) {
    float x = vp[v*3+0]+tx, y = vp[v*3+1]+ty, z = vp[v*3+2]+tz;
    o0[v] = x; o1[v] = y; o2[v] = z;
    mnx=fminf(mnx,x); mny=fminf(mny,y); mnz=fminf(mnz,z);
    mxx=fmaxf(mxx,x); mxy=fmaxf(mxy,y); mxz=fmaxf(mxz,z);
  }
  mnx=wave_min(mnx); mny=wave_min(mny); mnz=wave_min(mnz);
  mxx=wave_max(mxx); mxy=wave_max(mxy); mxz=wave_max(mxz);
  __shared__ float s[4][6];
  int wave = threadIdx.x >> 6, lane = threadIdx.x & 63;
  if (lane == 0) {
    s[wave][0]=mnx; s[wave][1]=mny; s[wave][2]=mnz;
    s[wave][3]=mxx; s[wave][4]=mxy; s[wave][5]=mxz;
  }
  __syncthreads();
  if (threadIdx.x == 0) {
    float a0=s[0][0],a1=s[0][1],a2=s[0][2],b0=s[0][3],b1=s[0][4],b2=s[0][5];
    for (int w = 1; w < 4; ++w) {
      a0=fminf(a0,s[w][0]); a1=fminf(a1,s[w][1]); a2=fminf(a2,s[w][2]);
      b0=fmaxf(b0,s[w][3]); b1=fmaxf(b1,s[w][4]); b2=fmaxf(b2,s[w][5]);
    }
    bbox[p*3+0]=a0; bbox[p*3+1]=a1; bbox[p*3+2]=a2;          // bmin
    bbox[192+p*3+0]=b0; bbox[192+p*3+1]=b1; bbox[192+p*3+2]=b2;  // bmax
  }
}

// -------- kernel 2: phi grid -> fp8 pair volume, z-slab + wave y-row cull ----
// block = 1024 threads (32x32 xy); 4 z-slabs of 8 planes per person.
__global__ __launch_bounds__(1024) void k_phi(
    const float* __restrict__ verts, const float* __restrict__ trans,
    const float* __restrict__ bbox, unsigned short* __restrict__ pairs) {
  int p = blockIdx.x >> 2;
  int zq = blockIdx.x & 3;
  int tid = threadIdx.x;
  int x = tid & 31, y = tid >> 5;

  __shared__ float kv[VSUB][3];       // z-culled vertex list
  __shared__ float phib[8][32][32];   // 32 KB
  __shared__ int nkeep;

  const float inv = 1.0f / (float)GRD;
  if (tid == 0) nkeep = 0;
  __syncthreads();

  // center/scale from bbox (k_setup folded in)
  float bx0 = bbox[p*3+0], by0 = bbox[p*3+1], bz0 = bbox[p*3+2];
  float bx1 = bbox[192+p*3+0], by1 = bbox[192+p*3+1], bz1 = bbox[192+p*3+2];
  float cx = 0.5f*(bx0+bx1), cy = 0.5f*(by0+by1), cz = 0.5f*(bz0+bz1);
  float ext = fmaxf(bx1-bx0, fmaxf(by1-by0, bz1-bz0));
  float is = 1.0f / (0.6f * ext);      // (1+0.2)*0.5 * ext

  // z-slab cull: vert can only matter if z-distance to slab range < BAND
  if (tid < VSUB) {
    int v = tid * VSTRIDE;
    const float* vp = verts + (size_t)p * NVERT * 3 + (size_t)v * 3;
    float X = (vp[0] + trans[p*3+0] - cx) * is;
    float Y = (vp[1] + trans[p*3+1] - cy) * is;
    float Z = (vp[2] + trans[p*3+2] - cz) * is;
    float zlo = (2.0f*(zq*8)     + 1.0f) * inv - 1.0f;
    float zhi = (2.0f*(zq*8 + 7) + 1.0f) * inv - 1.0f;
    float dz = fmaxf(fmaxf(zlo - Z, Z - zhi), 0.0f);
    if (dz < BAND) {
      int idx = atomicAdd(&nkeep, 1);
      kv[idx][0] = X; kv[idx][1] = Y; kv[idx][2] = Z;
    }
  }
  __syncthreads();
  int nk = nkeep;

  float gx = (2.0f*x + 1.0f) * inv - 1.0f;
  float gy = (2.0f*y + 1.0f) * inv - 1.0f;
  float gz[8];
  #pragma unroll
  for (int k = 0; k < 8; ++k) gz[k] = (2.0f*(zq*8+k) + 1.0f) * inv - 1.0f;

  float d2[8];
  #pragma unroll
  for (int k = 0; k < 8; ++k) d2[k] = 1e30f;

  // per-wave y-row cull: wave w owns rows y = {2w, 2w+1}; a vert with
  // y-distance >= BAND from these rows can't set phi there (d >= |dy|).
  int w = tid >> 6;
  float ylo = (4.0f*w + 1.0f) * inv - 1.0f;
  float yhi = (4.0f*w + 3.0f) * inv - 1.0f;

  for (int v = 0; v < nk; ++v) {
    float Y = kv[v][1];                          // broadcast read
    if (fmaxf(ylo - Y, Y - yhi) >= BAND) continue;   // wave-uniform skip
    float dx = gx - kv[v][0];
    float dy = gy - Y;
    float vz = kv[v][2];
    float r2 = fmaf(dy, dy, dx*dx);
    #pragma unroll
    for (int k = 0; k < 8; ++k) {
      float dz = gz[k] - vz;
      d2[k] = fminf(d2[k], fmaf(dz, dz, r2));
    }
  }
  #pragma unroll
  for (int k = 0; k < 8; ++k)
    phib[k][y][x] = fmaxf(BAND - sqrtf(d2[k]), 0.0f) * PHI_SCALE;
  __syncthreads();

  // pair assembly: u16 at (iz, iy, ix); gy = iy-1, gx = ix-1
  unsigned short* qp = pairs + (size_t)p * QVOL;
  for (int idx = tid; idx < QPLANE; idx += 1024) {
    int iy = idx / QDIM, ix = idx % QDIM;
    int gyy = iy - 1, gxx = ix - 1;
    bool gyok = (unsigned)gyy < 32u;
    bool aok = gyok && ((unsigned)gxx < 32u);
    bool bok = gyok && ((unsigned)ix  < 32u);
    int ya = gyok ? gyy : 0;
    int xa = aok ? gxx : 0;
    int xb = bok ? ix : 0;
    #pragma unroll
    for (int k = 0; k < 8; ++k) {
      float a = aok ? phib[k][ya][xa] : 0.0f;
      float b = bok ? phib[k][ya][xb] : 0.0f;
      int pk = __builtin_amdgcn_cvt_pk_fp8_f32(a, b, 0, false);
      qp[(zq*8 + k + 1)*QPLANE + idx] = (unsigned short)(pk & 0xffff);
    }
    if (zq == 0) qp[idx] = 0;                  // plane 0  (gz = -1)
    if (zq == 3) qp[33*QPLANE + idx] = 0;      // plane 33 (gz = 32)
  }
}

// -------- trilinear sample from the LDS pair volume --------
__device__ __forceinline__ float qsample(const unsigned short* q,
                                         float X, float Y, float Z) {
  X = fminf(fmaxf(X, 0.0f), 33.99f);
  Y = fminf(fmaxf(Y, 0.0f), 32.999f);
  Z = fminf(fmaxf(Z, 0.0f), 32.999f);
  float xf = floorf(X), yf = floorf(Y), zf = floorf(Z);
  float fx = X - xf, fy = Y - yf, fz = Z - zf;
  int e = ((int)zf * QDIM + (int)yf) * QDIM + (int)xf;
  unsigned int w00 = q[e];
  unsigned int w10 = q[e + QDIM];
  unsigned int w01 = q[e + QPLANE];
  unsigned int w11 = q[e + QPLANE + QDIM];
  floatx2 c00 = __builtin_amdgcn_cvt_pk_f32_fp8((int)w00, false);
  floatx2 c10 = __builtin_amdgcn_cvt_pk_f32_fp8((int)w10, false);
  floatx2 c01 = __builtin_amdgcn_cvt_pk_f32_fp8((int)w01, false);
  floatx2 c11 = __builtin_amdgcn_cvt_pk_f32_fp8((int)w11, false);
  float u00 = fmaf(fx, c00.y - c00.x, c00.x);
  float u10 = fmaf(fx, c10.y - c10.x, c10.x);
  float u01 = fmaf(fx, c01.y - c01.x, c01.x);
  float u11 = fmaf(fx, c11.y - c11.x, c11.x);
  float a0 = fmaf(fy, u10 - u00, u00);
  float a1 = fmaf(fy, u11 - u01, u01);
  return fmaf(fz, a1 - a0, a0);
}

// -------- kernel 3: sample + reduce + last-block finalize --------
__global__ __launch_bounds__(896, 7) void k_sample(
    const float* __restrict__ vertsT, const float* __restrict__ bbox,
    const unsigned short* __restrict__ pairs, float* __restrict__ accp,
    unsigned int* __restrict__ donep, float* __restrict__ out) {
  extern __shared__ unsigned char smem[];
  const unsigned short* sq = (const unsigned short*)smem;
  float* red = (float*)(smem + (size_t)QVOL * 2);
  unsigned long long* maskp = (unsigned long long*)(smem + (size_t)QVOL*2 + 64);

  int i = blockIdx.y;
  int tid = threadIdx.x;

  // stage all bboxes into LDS (transient; pair staging overwrites it later)
  float* sbb = (float*)smem;
  if (tid < 384) sbb[tid] = bbox[tid];
  __syncthreads();

  // wave 0: validity mask (k_setup folded in)
  if (tid < 64) {
    const float* smn = sbb;
    const float* smx = sbb + 192;
    bool valid = true;
    for (int j = 0; j < NP; ++j) {
      bool ov = true;
      #pragma unroll
      for (int c = 0; c < 3; ++c)
        ov = ov && (smn[tid*3+c] <= smx[j*3+c]) && (smn[j*3+c] <= smx[tid*3+c]);
      valid = valid && ov;
    }
    unsigned long long mm = __ballot(valid);
    if (tid == 0) *maskp = mm;
  }
  // per-thread center/scale of person i (read sbb before it's overwritten)
  float bx0 = sbb[i*3+0], by0 = sbb[i*3+1], bz0 = sbb[i*3+2];
  float bx1 = sbb[192+i*3+0], by1 = sbb[192+i*3+1], bz1 = sbb[192+i*3+2];
  float ext = fmaxf(bx1-bx0, fmaxf(by1-by0, bz1-bz0));
  float s16 = 16.0f / (0.6f * ext);
  float cx = 0.5f*(bx0+bx1), cy = 0.5f*(by0+by1), cz = 0.5f*(bz0+bz1);
  __syncthreads();
  unsigned long long mask = *maskp;   // maskp lives outside the pair area

  bool active = (mask >> i) & 1ull;
  if (active) {
    // stage pair volume (78608 B = 4913 uint4) into LDS
    const uint4* src = (const uint4*)(pairs + (size_t)i * QVOL);
    uint4* dst = (uint4*)smem;
    for (int t = tid; t < QVOL/8; t += 896) dst[t] = src[t];
    __syncthreads();

    int v = blockIdx.x * 896 + tid;
    bool ok = v < NVERT;
    int vc = ok ? v : 0;
    // +1 volume-index offset folded: 15.5 + 1 = 16.5
    float bx = fmaf(-cx, s16, 16.5f) + (ok ? 0.0f : 1e9f);
    float by = fmaf(-cy, s16, 16.5f);
    float bz = fmaf(-cz, s16, 16.5f);

    float acc = 0.0f;
    unsigned long long m = mask & ~(1ull << i);
    while (m) {
      int jj = (int)__builtin_ctzll(m);
      m &= m - 1;
      const float* p0 = vertsT + (size_t)(jj*3) * NVERT;
      float X = fmaf(p0[vc],         s16, bx);
      float Y = fmaf(p0[NVERT+vc],   s16, by);
      float Z = fmaf(p0[2*NVERT+vc], s16, bz);
      acc += qsample(sq, X, Y, Z);
    }

    acc = wave_sum(acc);
    int wv = tid >> 6, lane = tid & 63;
    if (lane == 0) red[wv] = acc;
    __syncthreads();
    if (tid == 0) {
      float tot = 0.0f;
      #pragma unroll
      for (int w = 0; w < 14; ++w) tot += red[w];
      atomicAdd(accp, tot * INV_PHI_SCALE);
    }
  }

  // last-block finalize (k_final folded in); every block increments
  if (tid == 0) {
    __threadfence();
    unsigned int old = atomicAdd(donep, 1u);
    if (old == SAMPLE_BLOCKS - 1) {
      float nv = fmaxf((float)__popcll(mask), 1.0f);
      float loss = atomicAdd(accp, 0.0f);      // coherent read
      out[0] = loss / (nv * nv);
    }
  }
}

extern "C" void kernel_launch(void* const* d_in, const int* in_sizes, int n_in,
                              void* d_out, int out_size, void* d_ws, size_t ws_size,
                              hipStream_t stream) {
  const float* verts = (const float*)d_in[0];   // [64,6890,3]
  const float* trans = (const float*)d_in[1];   // [64,3]
  float* out = (float*)d_out;

  unsigned short* pairs = (unsigned short*)d_ws;      // 64*39304*2 B = 5.03 MB
  float* vertsT    = (float*)((unsigned char*)d_ws + (size_t)NP * QVOL * 2);
  float* bbox      = vertsT + (size_t)NP * 3 * NVERT; // bmin[192] ++ bmax[192]
  float* accp      = bbox + 384;                      // loss accumulator
  unsigned int* donep = (unsigned int*)(accp + 1);    // done-block counter

  hipFuncSetAttribute((const void*)k_sample,
                      hipFuncAttributeMaxDynamicSharedMemorySize, LDS_BYTES);

  k_soa_bounds<<<NP, 256, 0, stream>>>(verts, trans, vertsT, bbox, accp, donep);
  k_phi<<<NP*4, 1024, 0, stream>>>(verts, trans, bbox, pairs);
  k_sample<<<dim3(8, NP), 896, LDS_BYTES, stream>>>(vertsT, bbox, pairs,
                                                    accp, donep, out);
}

// Round 12
// 118.112 us; speedup vs baseline: 2.5476x; 1.0102x over previous
//
#include <hip/hip_runtime.h>

// SDFLoss: P=64 people, V=6890 verts, 32^3 SDF-band proxy grid, trilinear
// cross-sampling, scalar loss.
//
// 3 kernels: k_soa_bounds (translated AoS verts + bbox + zero accumulators),
// k_phi (fp8 pair volume, z-slab + per-wave y-row culling), k_sample
// (validity mask + LDS jlist inline, LDS-staged pair volume, counted+unrolled
// prefetched j-loop, last-block finalize).
//
// phi: fully zero-padded PAIR volume, u16 at (iz,iy,ix), idx 0..33 = grid
// -1..32, holding (phi[gx], phi[gx+1]) as 2x fp8(e4m3) scaled x64.
// 34^3 x 2B = 78,608 B -> 2 blocks/CU in k_sample.

#define NP 64
#define NVERT 6890
#define NV3 (NVERT*3)
#define GRD 32
#define QDIM 34                   // -1..32 per axis
#define QPLANE (QDIM*QDIM)        // 1156 entries
#define QVOL (QDIM*QPLANE)        // 39304 entries = 78608 B
#define VSUB 256
#define VSTRIDE 26                // NVERT / VSUB
#define BAND 0.15f
#define PHI_SCALE 64.0f
#define INV_PHI_SCALE 0.015625f
#define OFF_RED  (QVOL*2)         // 14 floats
#define OFF_MASK (QVOL*2 + 64)    // u64
#define OFF_JL   (QVOL*2 + 80)    // u16[64]
#define LDS_BYTES (QVOL*2 + 224)  // 78832; x2 blocks = 157664 < 160 KiB
#define SAMPLE_BLOCKS (8*NP)

typedef float floatx2 __attribute__((ext_vector_type(2)));

__device__ __forceinline__ float wave_min(float v) {
  #pragma unroll
  for (int off = 32; off > 0; off >>= 1) v = fminf(v, __shfl_down(v, off));
  return v;
}
__device__ __forceinline__ float wave_max(float v) {
  #pragma unroll
  for (int off = 32; off > 0; off >>= 1) v = fmaxf(v, __shfl_down(v, off));
  return v;
}
__device__ __forceinline__ float wave_sum(float v) {
  #pragma unroll
  for (int off = 32; off > 0; off >>= 1) v += __shfl_down(v, off);
  return v;
}

// -------- kernel 1: translated AoS verts + bbox + zero accumulators --------
__global__ __launch_bounds__(256) void k_soa_bounds(
    const float* __restrict__ verts, const float* __restrict__ trans,
    float* __restrict__ vertsA, float* __restrict__ bbox,
    float* __restrict__ accp, unsigned int* __restrict__ donep) {
  int p = blockIdx.x;
  if (p == 0 && threadIdx.x == 0) { accp[0] = 0.0f; donep[0] = 0u; }
  const float* vp = verts + (size_t)p * NV3;
  float* op = vertsA + (size_t)p * NV3;
  float tx = trans[p*3+0], ty = trans[p*3+1], tz = trans[p*3+2];
  float mnx=1e30f, mny=1e30f, mnz=1e30f, mxx=-1e30f, mxy=-1e30f, mxz=-1e30f;
  for (int v = threadIdx.x; v < NVERT; v += blockDim.x) {
    float x = vp[v*3+0]+tx, y = vp[v*3+1]+ty, z = vp[v*3+2]+tz;
    op[v*3+0] = x; op[v*3+1] = y; op[v*3+2] = z;
    mnx=fminf(mnx,x); mny=fminf(mny,y); mnz=fminf(mnz,z);
    mxx=fmaxf(mxx,x); mxy=fmaxf(mxy,y); mxz=fmaxf(mxz,z);
  }
  mnx=wave_min(mnx); mny=wave_min(mny); mnz=wave_min(mnz);
  mxx=wave_max(mxx); mxy=wave_max(mxy); mxz=wave_max(mxz);
  __shared__ float s[4][6];
  int wave = threadIdx.x >> 6, lane = threadIdx.x & 63;
  if (lane == 0) {
    s[wave][0]=mnx; s[wave][1]=mny; s[wave][2]=mnz;
    s[wave][3]=mxx; s[wave][4]=mxy; s[wave][5]=mxz;
  }
  __syncthreads();
  if (threadIdx.x == 0) {
    float a0=s[0][0],a1=s[0][1],a2=s[0][2],b0=s[0][3],b1=s[0][4],b2=s[0][5];
    for (int w = 1; w < 4; ++w) {
      a0=fminf(a0,s[w][0]); a1=fminf(a1,s[w][1]); a2=fminf(a2,s[w][2]);
      b0=fmaxf(b0,s[w][3]); b1=fmaxf(b1,s[w][4]); b2=fmaxf(b2,s[w][5]);
    }
    bbox[p*3+0]=a0; bbox[p*3+1]=a1; bbox[p*3+2]=a2;              // bmin
    bbox[192+p*3+0]=b0; bbox[192+p*3+1]=b1; bbox[192+p*3+2]=b2;  // bmax
  }
}

// -------- kernel 2: phi grid -> fp8 pair volume, z-slab + wave y-row cull ----
__global__ __launch_bounds__(1024) void k_phi(
    const float* __restrict__ verts, const float* __restrict__ trans,
    const float* __restrict__ bbox, unsigned short* __restrict__ pairs) {
  int p = blockIdx.x >> 2;
  int zq = blockIdx.x & 3;
  int tid = threadIdx.x;
  int x = tid & 31, y = tid >> 5;

  __shared__ float kv[VSUB][3];       // z-culled vertex list
  __shared__ float phib[8][32][32];   // 32 KB
  __shared__ int nkeep;

  const float inv = 1.0f / (float)GRD;
  if (tid == 0) nkeep = 0;
  __syncthreads();

  // center/scale from bbox (k_setup folded in)
  float bx0 = bbox[p*3+0], by0 = bbox[p*3+1], bz0 = bbox[p*3+2];
  float bx1 = bbox[192+p*3+0], by1 = bbox[192+p*3+1], bz1 = bbox[192+p*3+2];
  float cx = 0.5f*(bx0+bx1), cy = 0.5f*(by0+by1), cz = 0.5f*(bz0+bz1);
  float ext = fmaxf(bx1-bx0, fmaxf(by1-by0, bz1-bz0));
  float is = 1.0f / (0.6f * ext);      // (1+0.2)*0.5 * ext

  // z-slab cull: vert can only matter if z-distance to slab range < BAND
  if (tid < VSUB) {
    int v = tid * VSTRIDE;
    const float* vp = verts + (size_t)p * NV3 + (size_t)v * 3;
    float X = (vp[0] + trans[p*3+0] - cx) * is;
    float Y = (vp[1] + trans[p*3+1] - cy) * is;
    float Z = (vp[2] + trans[p*3+2] - cz) * is;
    float zlo = (2.0f*(zq*8)     + 1.0f) * inv - 1.0f;
    float zhi = (2.0f*(zq*8 + 7) + 1.0f) * inv - 1.0f;
    float dz = fmaxf(fmaxf(zlo - Z, Z - zhi), 0.0f);
    if (dz < BAND) {
      int idx = atomicAdd(&nkeep, 1);
      kv[idx][0] = X; kv[idx][1] = Y; kv[idx][2] = Z;
    }
  }
  __syncthreads();
  int nk = nkeep;

  float gx = (2.0f*x + 1.0f) * inv - 1.0f;
  float gy = (2.0f*y + 1.0f) * inv - 1.0f;
  float gz[8];
  #pragma unroll
  for (int k = 0; k < 8; ++k) gz[k] = (2.0f*(zq*8+k) + 1.0f) * inv - 1.0f;

  float d2[8];
  #pragma unroll
  for (int k = 0; k < 8; ++k) d2[k] = 1e30f;

  // per-wave y-row cull: wave w owns rows y = {2w, 2w+1}
  int w = tid >> 6;
  float ylo = (4.0f*w + 1.0f) * inv - 1.0f;
  float yhi = (4.0f*w + 3.0f) * inv - 1.0f;

  for (int v = 0; v < nk; ++v) {
    float Y = kv[v][1];                              // broadcast read
    if (fmaxf(ylo - Y, Y - yhi) >= BAND) continue;   // wave-uniform skip
    float dx = gx - kv[v][0];
    float dy = gy - Y;
    float vz = kv[v][2];
    float r2 = fmaf(dy, dy, dx*dx);
    #pragma unroll
    for (int k = 0; k < 8; ++k) {
      float dz = gz[k] - vz;
      d2[k] = fminf(d2[k], fmaf(dz, dz, r2));
    }
  }
  #pragma unroll
  for (int k = 0; k < 8; ++k)
    phib[k][y][x] = fmaxf(BAND - sqrtf(d2[k]), 0.0f) * PHI_SCALE;
  __syncthreads();

  // pair assembly: u16 at (iz, iy, ix); gy = iy-1, gx = ix-1
  unsigned short* qp = pairs + (size_t)p * QVOL;
  for (int idx = tid; idx < QPLANE; idx += 1024) {
    int iy = idx / QDIM, ix = idx % QDIM;
    int gyy = iy - 1, gxx = ix - 1;
    bool gyok = (unsigned)gyy < 32u;
    bool aok = gyok && ((unsigned)gxx < 32u);
    bool bok = gyok && ((unsigned)ix  < 32u);
    int ya = gyok ? gyy : 0;
    int xa = aok ? gxx : 0;
    int xb = bok ? ix : 0;
    #pragma unroll
    for (int k = 0; k < 8; ++k) {
      float a = aok ? phib[k][ya][xa] : 0.0f;
      float b = bok ? phib[k][ya][xb] : 0.0f;
      int pk = __builtin_amdgcn_cvt_pk_fp8_f32(a, b, 0, false);
      qp[(zq*8 + k + 1)*QPLANE + idx] = (unsigned short)(pk & 0xffff);
    }
    if (zq == 0) qp[idx] = 0;                  // plane 0  (gz = -1)
    if (zq == 3) qp[33*QPLANE + idx] = 0;      // plane 33 (gz = 32)
  }
}

// -------- trilinear sample from the LDS pair volume --------
__device__ __forceinline__ float qsample(const unsigned short* q,
                                         float X, float Y, float Z) {
  X = fminf(fmaxf(X, 0.0f), 33.99f);
  Y = fminf(fmaxf(Y, 0.0f), 32.999f);
  Z = fminf(fmaxf(Z, 0.0f), 32.999f);
  float xf = floorf(X), yf = floorf(Y), zf = floorf(Z);
  float fx = X - xf, fy = Y - yf, fz = Z - zf;
  int e = ((int)zf * QDIM + (int)yf) * QDIM + (int)xf;
  unsigned int w00 = q[e];
  unsigned int w10 = q[e + QDIM];
  unsigned int w01 = q[e + QPLANE];
  unsigned int w11 = q[e + QPLANE + QDIM];
  floatx2 c00 = __builtin_amdgcn_cvt_pk_f32_fp8((int)w00, false);
  floatx2 c10 = __builtin_amdgcn_cvt_pk_f32_fp8((int)w10, false);
  floatx2 c01 = __builtin_amdgcn_cvt_pk_f32_fp8((int)w01, false);
  floatx2 c11 = __builtin_amdgcn_cvt_pk_f32_fp8((int)w11, false);
  float u00 = fmaf(fx, c00.y - c00.x, c00.x);
  float u10 = fmaf(fx, c10.y - c10.x, c10.x);
  float u01 = fmaf(fx, c01.y - c01.x, c01.x);
  float u11 = fmaf(fx, c11.y - c11.x, c11.x);
  float a0 = fmaf(fy, u10 - u00, u00);
  float a1 = fmaf(fy, u11 - u01, u01);
  return fmaf(fz, a1 - a0, a0);
}

// -------- kernel 3: sample + reduce + last-block finalize --------
__global__ __launch_bounds__(896, 7) void k_sample(
    const float* __restrict__ vertsA, const float* __restrict__ bbox,
    const unsigned short* __restrict__ pairs, float* __restrict__ accp,
    unsigned int* __restrict__ donep, float* __restrict__ out) {
  extern __shared__ unsigned char smem[];
  const unsigned short* sq = (const unsigned short*)smem;
  float* red = (float*)(smem + OFF_RED);
  unsigned long long* maskp = (unsigned long long*)(smem + OFF_MASK);
  unsigned short* sjl = (unsigned short*)(smem + OFF_JL);

  int i = blockIdx.y;
  int tid = threadIdx.x;

  // stage all bboxes into LDS (transient; pair staging overwrites it later)
  float* sbb = (float*)smem;
  if (tid < 384) sbb[tid] = bbox[tid];
  __syncthreads();

  // wave 0: validity mask + compacted jlist (valid j != i)
  if (tid < 64) {
    const float* smn = sbb;
    const float* smx = sbb + 192;
    bool valid = true;
    for (int j = 0; j < NP; ++j) {
      bool ov = true;
      #pragma unroll
      for (int c = 0; c < 3; ++c)
        ov = ov && (smn[tid*3+c] <= smx[j*3+c]) && (smn[j*3+c] <= smx[tid*3+c]);
      valid = valid && ov;
    }
    unsigned long long mm = __ballot(valid);
    if (tid == 0) *maskp = mm;
    unsigned long long mj = mm & ~(1ull << i);
    if (valid && tid != i) {
      int pos = (int)__popcll(mj & ((1ull << tid) - 1ull));
      sjl[pos] = (unsigned short)tid;
    }
  }
  // per-thread center/scale of person i (read sbb BEFORE pair staging)
  float bx0 = sbb[i*3+0], by0 = sbb[i*3+1], bz0 = sbb[i*3+2];
  float bx1 = sbb[192+i*3+0], by1 = sbb[192+i*3+1], bz1 = sbb[192+i*3+2];
  float ext = fmaxf(bx1-bx0, fmaxf(by1-by0, bz1-bz0));
  float s16 = 16.0f / (0.6f * ext);
  float cx = 0.5f*(bx0+bx1), cy = 0.5f*(by0+by1), cz = 0.5f*(bz0+bz1);
  __syncthreads();
  unsigned long long mask = *maskp;   // lives outside the pair area

  bool active = (mask >> i) & 1ull;
  int cnt = (int)__popcll(mask & ~(1ull << i));
  if (active && cnt > 0) {
    // stage pair volume (78608 B = 4913 uint4) into LDS
    const uint4* src = (const uint4*)(pairs + (size_t)i * QVOL);
    uint4* dst = (uint4*)smem;
    for (int t = tid; t < QVOL/8; t += 896) dst[t] = src[t];
    __syncthreads();

    int v = blockIdx.x * 896 + tid;
    bool ok = v < NVERT;
    int vc3 = (ok ? v : 0) * 3;
    // +1 volume-index offset folded: 15.5 + 1 = 16.5
    float bx = fmaf(-cx, s16, 16.5f) + (ok ? 0.0f : 1e9f);
    float by = fmaf(-cy, s16, 16.5f);
    float bz = fmaf(-cz, s16, 16.5f);

    float acc = 0.0f;
    // counted, unrollable, software-pipelined j-loop
    int jj = __builtin_amdgcn_readfirstlane((int)sjl[0]);
    const float* pj = vertsA + (size_t)jj * NV3 + vc3;
    float x0 = pj[0], y0 = pj[1], z0 = pj[2];
    #pragma unroll 2
    for (int t = 0; t < cnt; ++t) {
      int tn = (t + 1 < cnt) ? t + 1 : t;
      int jn = __builtin_amdgcn_readfirstlane((int)sjl[tn]);
      const float* pn = vertsA + (size_t)jn * NV3 + vc3;
      float xn = pn[0], yn = pn[1], zn = pn[2];
      acc += qsample(sq, fmaf(x0, s16, bx), fmaf(y0, s16, by),
                     fmaf(z0, s16, bz));
      x0 = xn; y0 = yn; z0 = zn;
    }

    acc = wave_sum(acc);
    int wv = tid >> 6, lane = tid & 63;
    if (lane == 0) red[wv] = acc;
    __syncthreads();
    if (tid == 0) {
      float tot = 0.0f;
      #pragma unroll
      for (int w = 0; w < 14; ++w) tot += red[w];
      atomicAdd(accp, tot * INV_PHI_SCALE);
    }
  }

  // last-block finalize; every block increments
  if (tid == 0) {
    __threadfence();
    unsigned int old = atomicAdd(donep, 1u);
    if (old == SAMPLE_BLOCKS - 1) {
      float nv = fmaxf((float)__popcll(mask), 1.0f);
      float loss = atomicAdd(accp, 0.0f);      // coherent read
      out[0] = loss / (nv * nv);
    }
  }
}

extern "C" void kernel_launch(void* const* d_in, const int* in_sizes, int n_in,
                              void* d_out, int out_size, void* d_ws, size_t ws_size,
                              hipStream_t stream) {
  const float* verts = (const float*)d_in[0];   // [64,6890,3]
  const float* trans = (const float*)d_in[1];   // [64,3]
  float* out = (float*)d_out;

  unsigned short* pairs = (unsigned short*)d_ws;      // 64*39304*2 B = 5.03 MB
  float* vertsA    = (float*)((unsigned char*)d_ws + (size_t)NP * QVOL * 2);
  float* bbox      = vertsA + (size_t)NP * NV3;       // bmin[192] ++ bmax[192]
  float* accp      = bbox + 384;                      // loss accumulator
  unsigned int* donep = (unsigned int*)(accp + 1);    // done-block counter

  hipFuncSetAttribute((const void*)k_sample,
                      hipFuncAttributeMaxDynamicSharedMemorySize, LDS_BYTES);

  k_soa_bounds<<<NP, 256, 0, stream>>>(verts, trans, vertsA, bbox, accp, donep);
  k_phi<<<NP*4, 1024, 0, stream>>>(verts, trans, bbox, pairs);
  k_sample<<<dim3(8, NP), 896, LDS_BYTES, stream>>>(vertsA, bbox, pairs,
                                                    accp, donep, out);
}

// Round 13
// 106.772 us; speedup vs baseline: 2.8182x; 1.1062x over previous
//
#include <hip/hip_runtime.h>

// SDFLoss: P=64 people, V=6890 verts, 32^3 SDF-band proxy grid, trilinear
// cross-sampling, scalar loss.
//
// 3 kernels:
//   k_soa_bounds : SoA verts (translation folded) + bbox + zero accumulators
//   k_phi        : fp8 pair volume (z-slab + wave y-row culls); block 0 also
//                  computes validity mask / jlist / nv / per-person center+s16
//   k_sample     : round-10-shape j-loop (global scalar jlist, counted,
//                  unroll 2, no loop-carried LDS/indirection) + last-block
//                  finalize.
//
// phi: fully zero-padded PAIR volume, u16 at (iz,iy,ix), idx 0..33 = grid
// -1..32, holding (phi[gx], phi[gx+1]) as 2x fp8(e4m3) scaled x64.
// 34^3 x 2B = 78,608 B -> 2 blocks/CU in k_sample.

#define NP 64
#define NVERT 6890
#define NV3 (NVERT*3)
#define GRD 32
#define QDIM 34                   // -1..32 per axis
#define QPLANE (QDIM*QDIM)        // 1156 entries
#define QVOL (QDIM*QPLANE)        // 39304 entries = 78608 B
#define VSUB 256
#define VSTRIDE 26                // NVERT / VSUB
#define BAND 0.15f
#define PHI_SCALE 64.0f
#define INV_PHI_SCALE 0.015625f
#define LDS_BYTES (QVOL*2 + 64)
#define SAMPLE_BLOCKS (8*NP)

typedef float floatx2 __attribute__((ext_vector_type(2)));

__device__ __forceinline__ float wave_min(float v) {
  #pragma unroll
  for (int off = 32; off > 0; off >>= 1) v = fminf(v, __shfl_down(v, off));
  return v;
}
__device__ __forceinline__ float wave_max(float v) {
  #pragma unroll
  for (int off = 32; off > 0; off >>= 1) v = fmaxf(v, __shfl_down(v, off));
  return v;
}
__device__ __forceinline__ float wave_sum(float v) {
  #pragma unroll
  for (int off = 32; off > 0; off >>= 1) v += __shfl_down(v, off);
  return v;
}

// -------- kernel 1: SoA verts (translation folded) + bbox + zero accs --------
__global__ __launch_bounds__(256) void k_soa_bounds(
    const float* __restrict__ verts, const float* __restrict__ trans,
    float* __restrict__ vertsT, float* __restrict__ bbox,
    float* __restrict__ accp, unsigned int* __restrict__ donep) {
  int p = blockIdx.x;
  if (p == 0 && threadIdx.x == 0) { accp[0] = 0.0f; donep[0] = 0u; }
  const float* vp = verts + (size_t)p * NV3;
  float tx = trans[p*3+0], ty = trans[p*3+1], tz = trans[p*3+2];
  float* o0 = vertsT + (size_t)(p*3+0) * NVERT;
  float* o1 = vertsT + (size_t)(p*3+1) * NVERT;
  float* o2 = vertsT + (size_t)(p*3+2) * NVERT;
  float mnx=1e30f, mny=1e30f, mnz=1e30f, mxx=-1e30f, mxy=-1e30f, mxz=-1e30f;
  for (int v = threadIdx.x; v < NVERT; v += blockDim.x) {
    float x = vp[v*3+0]+tx, y = vp[v*3+1]+ty, z = vp[v*3+2]+tz;
    o0[v] = x; o1[v] = y; o2[v] = z;
    mnx=fminf(mnx,x); mny=fminf(mny,y); mnz=fminf(mnz,z);
    mxx=fmaxf(mxx,x); mxy=fmaxf(mxy,y); mxz=fmaxf(mxz,z);
  }
  mnx=wave_min(mnx); mny=wave_min(mny); mnz=wave_min(mnz);
  mxx=wave_max(mxx); mxy=wave_max(mxy); mxz=wave_max(mxz);
  __shared__ float s[4][6];
  int wave = threadIdx.x >> 6, lane = threadIdx.x & 63;
  if (lane == 0) {
    s[wave][0]=mnx; s[wave][1]=mny; s[wave][2]=mnz;
    s[wave][3]=mxx; s[wave][4]=mxy; s[wave][5]=mxz;
  }
  __syncthreads();
  if (threadIdx.x == 0) {
    float a0=s[0][0],a1=s[0][1],a2=s[0][2],b0=s[0][3],b1=s[0][4],b2=s[0][5];
    for (int w = 1; w < 4; ++w) {
      a0=fminf(a0,s[w][0]); a1=fminf(a1,s[w][1]); a2=fminf(a2,s[w][2]);
      b0=fmaxf(b0,s[w][3]); b1=fmaxf(b1,s[w][4]); b2=fmaxf(b2,s[w][5]);
    }
    bbox[p*3+0]=a0; bbox[p*3+1]=a1; bbox[p*3+2]=a2;              // bmin
    bbox[192+p*3+0]=b0; bbox[192+p*3+1]=b1; bbox[192+p*3+2]=b2;  // bmax
  }
}

// -------- kernel 2: phi pair volume + (block 0) setup outputs --------
__global__ __launch_bounds__(1024) void k_phi(
    const float* __restrict__ verts, const float* __restrict__ trans,
    const float* __restrict__ bbox, unsigned short* __restrict__ pairs,
    float* __restrict__ centerg,   // [NP][4] = cx,cy,cz,s16
    float* __restrict__ validg, int* __restrict__ jlistg,
    int* __restrict__ jcountg, float* __restrict__ nvg) {
  int p = blockIdx.x >> 2;
  int zq = blockIdx.x & 3;
  int tid = threadIdx.x;
  int x = tid & 31, y = tid >> 5;

  __shared__ float kv[VSUB][3];       // z-culled vertex list
  __shared__ float phib[8][32][32];   // 32 KB
  __shared__ int nkeep;

  const float inv = 1.0f / (float)GRD;
  if (tid == 0) nkeep = 0;
  __syncthreads();

  // center/scale from bbox
  float bx0 = bbox[p*3+0], by0 = bbox[p*3+1], bz0 = bbox[p*3+2];
  float bx1 = bbox[192+p*3+0], by1 = bbox[192+p*3+1], bz1 = bbox[192+p*3+2];
  float cx = 0.5f*(bx0+bx1), cy = 0.5f*(by0+by1), cz = 0.5f*(bz0+bz1);
  float ext = fmaxf(bx1-bx0, fmaxf(by1-by0, bz1-bz0));
  float is = 1.0f / (0.6f * ext);      // (1+0.2)*0.5 * ext

  // zq==0 block publishes person p's center + sample scale
  if (zq == 0 && tid == 0) {
    centerg[p*4+0] = cx; centerg[p*4+1] = cy; centerg[p*4+2] = cz;
    centerg[p*4+3] = is * 16.0f;
  }
  // block 0, wave 0: validity mask / jlist / counts (old k_setup)
  if (blockIdx.x == 0 && tid < 64) {
    bool valid = true;
    for (int j = 0; j < NP; ++j) {
      bool ov = true;
      #pragma unroll
      for (int c = 0; c < 3; ++c)
        ov = ov && (bbox[tid*3+c] <= bbox[192+j*3+c]) &&
                   (bbox[j*3+c] <= bbox[192+tid*3+c]);
      valid = valid && ov;
    }
    unsigned long long mm = __ballot(valid);
    if (valid) {
      int pos = (int)__popcll(mm & ((1ull << tid) - 1ull));
      jlistg[pos] = tid;
    }
    validg[tid] = valid ? 1.0f : 0.0f;
    if (tid == 0) {
      jcountg[0] = (int)__popcll(mm);
      nvg[0] = (float)__popcll(mm);
    }
  }

  // z-slab cull: vert can only matter if z-distance to slab range < BAND
  if (tid < VSUB) {
    int v = tid * VSTRIDE;
    const float* vp = verts + (size_t)p * NV3 + (size_t)v * 3;
    float X = (vp[0] + trans[p*3+0] - cx) * is;
    float Y = (vp[1] + trans[p*3+1] - cy) * is;
    float Z = (vp[2] + trans[p*3+2] - cz) * is;
    float zlo = (2.0f*(zq*8)     + 1.0f) * inv - 1.0f;
    float zhi = (2.0f*(zq*8 + 7) + 1.0f) * inv - 1.0f;
    float dz = fmaxf(fmaxf(zlo - Z, Z - zhi), 0.0f);
    if (dz < BAND) {
      int idx = atomicAdd(&nkeep, 1);
      kv[idx][0] = X; kv[idx][1] = Y; kv[idx][2] = Z;
    }
  }
  __syncthreads();
  int nk = nkeep;

  float gx = (2.0f*x + 1.0f) * inv - 1.0f;
  float gy = (2.0f*y + 1.0f) * inv - 1.0f;
  float gz[8];
  #pragma unroll
  for (int k = 0; k < 8; ++k) gz[k] = (2.0f*(zq*8+k) + 1.0f) * inv - 1.0f;

  float d2[8];
  #pragma unroll
  for (int k = 0; k < 8; ++k) d2[k] = 1e30f;

  // per-wave y-row cull: wave w owns rows y = {2w, 2w+1}
  int w = tid >> 6;
  float ylo = (4.0f*w + 1.0f) * inv - 1.0f;
  float yhi = (4.0f*w + 3.0f) * inv - 1.0f;

  for (int v = 0; v < nk; ++v) {
    float Y = kv[v][1];                              // broadcast read
    if (fmaxf(ylo - Y, Y - yhi) >= BAND) continue;   // wave-uniform skip
    float dx = gx - kv[v][0];
    float dy = gy - Y;
    float vz = kv[v][2];
    float r2 = fmaf(dy, dy, dx*dx);
    #pragma unroll
    for (int k = 0; k < 8; ++k) {
      float dz = gz[k] - vz;
      d2[k] = fminf(d2[k], fmaf(dz, dz, r2));
    }
  }
  #pragma unroll
  for (int k = 0; k < 8; ++k)
    phib[k][y][x] = fmaxf(BAND - sqrtf(d2[k]), 0.0f) * PHI_SCALE;
  __syncthreads();

  // pair assembly: u16 at (iz, iy, ix); gy = iy-1, gx = ix-1
  unsigned short* qp = pairs + (size_t)p * QVOL;
  for (int idx = tid; idx < QPLANE; idx += 1024) {
    int iy = idx / QDIM, ix = idx % QDIM;
    int gyy = iy - 1, gxx = ix - 1;
    bool gyok = (unsigned)gyy < 32u;
    bool aok = gyok && ((unsigned)gxx < 32u);
    bool bok = gyok && ((unsigned)ix  < 32u);
    int ya = gyok ? gyy : 0;
    int xa = aok ? gxx : 0;
    int xb = bok ? ix : 0;
    #pragma unroll
    for (int k = 0; k < 8; ++k) {
      float a = aok ? phib[k][ya][xa] : 0.0f;
      float b = bok ? phib[k][ya][xb] : 0.0f;
      int pk = __builtin_amdgcn_cvt_pk_fp8_f32(a, b, 0, false);
      qp[(zq*8 + k + 1)*QPLANE + idx] = (unsigned short)(pk & 0xffff);
    }
    if (zq == 0) qp[idx] = 0;                  // plane 0  (gz = -1)
    if (zq == 3) qp[33*QPLANE + idx] = 0;      // plane 33 (gz = 32)
  }
}

// -------- trilinear sample from the LDS pair volume --------
__device__ __forceinline__ float qsample(const unsigned short* q,
                                         float X, float Y, float Z) {
  X = fminf(fmaxf(X, 0.0f), 33.99f);
  Y = fminf(fmaxf(Y, 0.0f), 32.999f);
  Z = fminf(fmaxf(Z, 0.0f), 32.999f);
  float xf = floorf(X), yf = floorf(Y), zf = floorf(Z);
  float fx = X - xf, fy = Y - yf, fz = Z - zf;
  int e = ((int)zf * QDIM + (int)yf) * QDIM + (int)xf;
  unsigned int w00 = q[e];
  unsigned int w10 = q[e + QDIM];
  unsigned int w01 = q[e + QPLANE];
  unsigned int w11 = q[e + QPLANE + QDIM];
  floatx2 c00 = __builtin_amdgcn_cvt_pk_f32_fp8((int)w00, false);
  floatx2 c10 = __builtin_amdgcn_cvt_pk_f32_fp8((int)w10, false);
  floatx2 c01 = __builtin_amdgcn_cvt_pk_f32_fp8((int)w01, false);
  floatx2 c11 = __builtin_amdgcn_cvt_pk_f32_fp8((int)w11, false);
  float u00 = fmaf(fx, c00.y - c00.x, c00.x);
  float u10 = fmaf(fx, c10.y - c10.x, c10.x);
  float u01 = fmaf(fx, c01.y - c01.x, c01.x);
  float u11 = fmaf(fx, c11.y - c11.x, c11.x);
  float a0 = fmaf(fy, u10 - u00, u00);
  float a1 = fmaf(fy, u11 - u01, u01);
  return fmaf(fz, a1 - a0, a0);
}

// -------- kernel 3: sample + reduce + last-block finalize --------
__global__ __launch_bounds__(896, 7) void k_sample(
    const float* __restrict__ vertsT, const float* __restrict__ centerg,
    const float* __restrict__ validg, const unsigned short* __restrict__ pairs,
    const int* __restrict__ jlistg, const int* __restrict__ jcountg,
    const float* __restrict__ nvg, float* __restrict__ accp,
    unsigned int* __restrict__ donep, float* __restrict__ out) {
  extern __shared__ unsigned char smem[];
  const unsigned short* sq = (const unsigned short*)smem;
  float* red = (float*)(smem + (size_t)QVOL * 2);

  int i = blockIdx.y;
  int tid = threadIdx.x;
  int njl = jcountg[0];

  if (validg[i] != 0.0f) {
    // stage pair volume (78608 B = 4913 uint4) into LDS, immediately
    {
      const uint4* src = (const uint4*)(pairs + (size_t)i * QVOL);
      uint4* dst = (uint4*)smem;
      for (int t = tid; t < QVOL/8; t += 896) dst[t] = src[t];
    }
    __syncthreads();

    int v = blockIdx.x * 896 + tid;
    bool ok = v < NVERT;
    int vc = ok ? v : 0;
    float s16 = centerg[i*4+3];
    // +1 volume-index offset folded: 15.5 + 1 = 16.5
    float bx = fmaf(-centerg[i*4+0], s16, 16.5f) + (ok ? 0.0f : 1e9f);
    float by = fmaf(-centerg[i*4+1], s16, 16.5f);
    float bz = fmaf(-centerg[i*4+2], s16, 16.5f);

    float acc = 0.0f;
    #pragma unroll 2
    for (int t = 0; t < njl; ++t) {
      int jj = jlistg[t];                      // uniform -> scalar load/branch
      if (jj == i) continue;
      const float* p0 = vertsT + (size_t)(jj*3) * NVERT;
      float X = fmaf(p0[vc],         s16, bx);
      float Y = fmaf(p0[NVERT+vc],   s16, by);
      float Z = fmaf(p0[2*NVERT+vc], s16, bz);
      acc += qsample(sq, X, Y, Z);
    }

    acc = wave_sum(acc);
    int wv = tid >> 6, lane = tid & 63;
    if (lane == 0) red[wv] = acc;
    __syncthreads();
    if (tid == 0) {
      float tot = 0.0f;
      #pragma unroll
      for (int w = 0; w < 14; ++w) tot += red[w];
      atomicAdd(accp, tot * INV_PHI_SCALE);
    }
  }

  // last-block finalize; every block increments
  if (tid == 0) {
    __threadfence();
    unsigned int old = atomicAdd(donep, 1u);
    if (old == SAMPLE_BLOCKS - 1) {
      float nv = fmaxf(nvg[0], 1.0f);
      float loss = atomicAdd(accp, 0.0f);      // coherent read
      out[0] = loss / (nv * nv);
    }
  }
}

extern "C" void kernel_launch(void* const* d_in, const int* in_sizes, int n_in,
                              void* d_out, int out_size, void* d_ws, size_t ws_size,
                              hipStream_t stream) {
  const float* verts = (const float*)d_in[0];   // [64,6890,3]
  const float* trans = (const float*)d_in[1];   // [64,3]
  float* out = (float*)d_out;

  unsigned short* pairs = (unsigned short*)d_ws;      // 64*39304*2 B = 5.03 MB
  float* vertsT    = (float*)((unsigned char*)d_ws + (size_t)NP * QVOL * 2);
  float* bbox      = vertsT + (size_t)NP * NV3;       // bmin[192] ++ bmax[192]
  float* centerg   = bbox + 384;                      // [NP][4]
  float* validg    = centerg + NP*4;
  float* nvg       = validg + NP;
  float* accp      = nvg + 1;
  unsigned int* donep = (unsigned int*)(accp + 1);
  int* jlistg      = (int*)(donep + 1);
  int* jcountg     = jlistg + NP;

  hipFuncSetAttribute((const void*)k_sample,
                      hipFuncAttributeMaxDynamicSharedMemorySize, LDS_BYTES);

  k_soa_bounds<<<NP, 256, 0, stream>>>(verts, trans, vertsT, bbox, accp, donep);
  k_phi<<<NP*4, 1024, 0, stream>>>(verts, trans, bbox, pairs, centerg,
                                   validg, jlistg, jcountg, nvg);
  k_sample<<<dim3(8, NP), 896, LDS_BYTES, stream>>>(vertsT, centerg, validg,
                                                    pairs, jlistg, jcountg,
                                                    nvg, accp, donep, out);
}